// Round 13
// baseline (387.409 us; speedup 1.0000x reference)
//
#include <hip/hip_runtime.h>
#include <hip/hip_fp16.h>
#include <math.h>

// ---------------------------------------------------------------------------
// GAT model forward. N=100k nodes, E=1.6M edges, HID=64.
// R12 changes vs R11 (which tied best at 384.1us):
//  - k_scatter: first histogram atomicAdd's return value is the edge's rank
//    within (block,bucket) -> position = base + rank; second LDS atomic pass
//    and one barrier removed (halves LDS atomics / bank conflicts).
//  - k_bucket_build: same rank trick (rank LDS array) kills its second
//    atomic pass, AND it now emits layer-1 palpha4 (fp16) during the rewrite
//    -> k_palpha<4> launch + 6.4MB ebuf re-read eliminated. 10 -> 9 dispatches.
//  - gather kernels untouched: edge head at structural 8-XCD replication
//    floor (~184MB / 3.1TB/s); agg structure = R8 local optimum (R9/R10
//    fusion & pairing both regressed via occupancy).
// ---------------------------------------------------------------------------

typedef _Float16 half8_t __attribute__((ext_vector_type(8)));
typedef _Float16 half4_t __attribute__((ext_vector_type(4)));
typedef float floatx4 __attribute__((ext_vector_type(4)));

// Phase 1: bucket edges by dst>>7. Block 0 also computes Mc=[encW@g1W;encb@g1W].
// Rank trick: r = atomicAdd(hist) in the count pass IS the in-block rank.
__global__ void k_scatter(const int* __restrict__ src, const int* __restrict__ dst,
                          int E, int NB, int cap, int* cursor,
                          unsigned int* __restrict__ ebuf,
                          const float* __restrict__ encW, const float* __restrict__ encb,
                          const float* __restrict__ g1W, float* __restrict__ Mc){
  __shared__ int hist[800];
  __shared__ int base[800];
  int t = threadIdx.x;                  // blockDim = 256
  if (blockIdx.x == 0 && t < 64){
    float m0 = 0.f, m1 = 0.f, cc = 0.f;
    for (int k = 0; k < 64; ++k){
      float g = g1W[k * 64 + t];
      m0 = fmaf(encW[k], g, m0);
      m1 = fmaf(encW[64 + k], g, m1);
      cc = fmaf(encb[k], g, cc);
    }
    Mc[t] = m0; Mc[64 + t] = m1; Mc[128 + t] = cc;
  }
  for (int i = t; i < NB; i += 256) hist[i] = 0;
  __syncthreads();
  int cbase = blockIdx.x * 2048;
  int sv[8], bk[8], dl[8], rk[8];
  #pragma unroll
  for (int i = 0; i < 8; ++i){
    int e = cbase + i * 256 + t;
    if (e < E){
      int d = dst[e];
      sv[i] = src[e]; bk[i] = d >> 7; dl[i] = d & 127;
      rk[i] = atomicAdd(&hist[bk[i]], 1);   // rank within (block,bucket)
    } else bk[i] = -1;
  }
  __syncthreads();
  for (int i = t; i < NB; i += 256){
    int c = hist[i];
    base[i] = (c > 0) ? (i * cap + atomicAdd(&cursor[i], c)) : 0;
  }
  __syncthreads();
  #pragma unroll
  for (int i = 0; i < 8; ++i){
    if (bk[i] >= 0){
      int p = base[bk[i]] + rk[i];
      if (p < (bk[i] + 1) * cap)        // overflow guard (never fires in practice)
        ebuf[p] = (unsigned)sv[i] | ((unsigned)dl[i] << 17);
    }
  }
}

// Phase 2: one block (256 thr) per 128-node bucket. Sort in LDS ->
// rstart/rend + dst-sorted packed ebuf, AND emit layer-1 palpha4 (fp16).
// Rank trick: per-node rank from the single histogram atomic pass.
__global__ void k_bucket_build(const int* __restrict__ cursor, int cap, int N,
                               unsigned int* ebuf, int* __restrict__ rstart,
                               int* __restrict__ rend,
                               const float* __restrict__ as4,
                               const float* __restrict__ ad4,
                               half4_t* __restrict__ palpha4){
  __shared__ unsigned int ent[2700];
  __shared__ unsigned short rank[2700];
  __shared__ int cnts[128];
  __shared__ int aux[128];
  int b = blockIdx.x, t = threadIdx.x;  // blockDim = 256
  int base = b * cap;
  int cnt = cursor[b];
  if (cnt > cap) cnt = cap;
  for (int i = t; i < cnt; i += 256) ent[i] = ebuf[base + i];
  if (t < 128) cnts[t] = 0;
  __syncthreads();
  for (int i = t; i < cnt; i += 256)
    rank[i] = (unsigned short)atomicAdd(&cnts[ent[i] >> 17], 1);
  __syncthreads();
  int v = 0;
  if (t < 128){ v = cnts[t]; aux[t] = v; }
  __syncthreads();
  for (int off = 1; off < 128; off <<= 1){
    int x = 0;
    if (t < 128 && t >= off) x = aux[t - off];
    __syncthreads();
    if (t < 128) aux[t] += x;
    __syncthreads();
  }
  if (t < 128){
    int incl = aux[t];
    int node = (b << 7) + t;
    if (node < N){ rstart[node] = base + incl - v; rend[node] = base + incl; }
    cnts[t] = incl - v;                 // per-node segment start (no atomics)
  }
  __syncthreads();
  for (int i = t; i < cnt; i += 256){
    unsigned int en = ent[i];
    int dl = en >> 17;
    int s = en & 0x1FFFFu;
    int pos = cnts[dl] + (int)rank[i];
    ebuf[base + pos] = en;              // keep packed (src|dl<<17)
    int d = (b << 7) + dl;
    float4 sv = ((const float4*)as4)[s];
    float4 dv = ((const float4*)ad4)[d];
    float a0 = sv.x + dv.x, a1 = sv.y + dv.y, a2 = sv.z + dv.z, a3 = sv.w + dv.w;
    a0 = a0 > 0.f ? a0 : 0.2f * a0;
    a1 = a1 > 0.f ? a1 : 0.2f * a1;
    a2 = a2 > 0.f ? a2 : 0.2f * a2;
    a3 = a3 > 0.f ? a3 : 0.2f * a3;
    half4_t pv = {(_Float16)__expf(a0), (_Float16)__expf(a1),
                  (_Float16)__expf(a2), (_Float16)__expf(a3)};
    palpha4[base + pos] = pv;
  }
}

// layer-2 per-edge numerators (fp16), edge-parallel over sorted ebuf.
__global__ void k_palpha1(const int* __restrict__ cursor, int cap,
                          const unsigned int* __restrict__ ebuf,
                          const float* __restrict__ as, const float* __restrict__ ad,
                          _Float16* __restrict__ palpha1){
  int blk = blockIdx.x;
  int b = blk >> 2, part = blk & 3;
  int base = b * cap;
  int cnt = cursor[b];
  if (cnt > cap) cnt = cap;
  for (int i = part * 256 + threadIdx.x; i < cnt; i += 1024){
    unsigned int en = ebuf[base + i];
    int s = en & 0x1FFFFu;
    int d = (b << 7) + (en >> 17);
    float a = as[s] + ad[d];
    a = a > 0.f ? a : 0.2f * a;
    palpha1[base + i] = (_Float16)__expf(a);
  }
}

// hw1 = fp16(x @ M + c); alpha for H=4 heads (C=16)
__global__ void k_fuse1(const float* __restrict__ x, const float* __restrict__ Mc,
                        const float* __restrict__ a_s, const float* __restrict__ a_d,
                        __half* __restrict__ hw, float* __restrict__ alpha_s,
                        float* __restrict__ alpha_d, int n){
  int idx = blockIdx.x * blockDim.x + threadIdx.x;
  if (idx >= n * 64) return;
  int node = idx >> 6, j = idx & 63;
  float acc = fmaf(x[node * 2 + 0], Mc[j], fmaf(x[node * 2 + 1], Mc[64 + j], Mc[128 + j]));
  hw[idx] = __float2half(acc);
  float ps = acc * a_s[j];
  float pd = acc * a_d[j];
  #pragma unroll
  for (int off = 1; off < 16; off <<= 1){
    ps += __shfl_xor(ps, off);
    pd += __shfl_xor(pd, off);
  }
  if ((j & 15) == 0){
    int h = j >> 4;
    alpha_s[node * 4 + h] = ps;
    alpha_d[node * 4 + h] = pd;
  }
}

// MFMA GEMM: hw2 = fp16(h1 @ g2W); alpha_s/d (H=1) = rowsum(hw2 * a_{s,d}).
__global__ __launch_bounds__(256) void k_hw_mfma(
    const __half* __restrict__ hin, const float* __restrict__ W,
    const float* __restrict__ a_s, const float* __restrict__ a_d,
    __half* __restrict__ hw, float* __restrict__ alpha_s,
    float* __restrict__ alpha_d, int n){
  __shared__ float redS[4][16];
  __shared__ float redD[4][16];
  int t = threadIdx.x;
  int lane = t & 63, wave = t >> 6;
  int l15 = lane & 15, quad = lane >> 4;
  int ch = wave * 16 + l15;
  half8_t b0, b1;
  #pragma unroll
  for (int j = 0; j < 8; ++j){
    b0[j] = (_Float16)W[(quad * 8 + j) * 64 + ch];
    b1[j] = (_Float16)W[(quad * 8 + j + 32) * 64 + ch];
  }
  float asv = a_s[ch], adv = a_d[ch];
  int base = blockIdx.x * 64;
  for (int it = 0; it < 4; ++it){
    int tb = base + it * 16;
    if (tb >= n) break;
    int arn = tb + l15; if (arn >= n) arn = n - 1;
    const __half* arow = hin + (size_t)arn * 64 + quad * 8;
    half8_t a0 = *(const half8_t*)arow;
    half8_t a1 = *(const half8_t*)(arow + 32);
    floatx4 acc = {0.f, 0.f, 0.f, 0.f};
    acc = __builtin_amdgcn_mfma_f32_16x16x32_f16(a0, b0, acc, 0, 0, 0);
    acc = __builtin_amdgcn_mfma_f32_16x16x32_f16(a1, b1, acc, 0, 0, 0);
    float ps[4], pd[4];
    #pragma unroll
    for (int r = 0; r < 4; ++r){
      int node = tb + quad * 4 + r;
      if (node < n) hw[(size_t)node * 64 + ch] = __float2half(acc[r]);
      ps[r] = acc[r] * asv;
      pd[r] = acc[r] * adv;
      #pragma unroll
      for (int off = 1; off < 16; off <<= 1){
        ps[r] += __shfl_xor(ps[r], off);
        pd[r] += __shfl_xor(pd[r], off);
      }
    }
    if (l15 == 0){
      #pragma unroll
      for (int r = 0; r < 4; ++r){
        redS[wave][quad * 4 + r] = ps[r];
        redD[wave][quad * 4 + r] = pd[r];
      }
    }
    __syncthreads();
    if (t < 16 && tb + t < n){
      alpha_s[tb + t] = redS[0][t] + redS[1][t] + redS[2][t] + redS[3][t];
      alpha_d[tb + t] = redD[0][t] + redD[1][t] + redD[2][t] + redD[3][t];
    }
    __syncthreads();
  }
}

// Wave = 1 destination node, 8 edge-groups x 8 lanes; lane jj owns channels
// 8jj..8jj+7 (one 16B fp16 load per edge). Serial loop = ebuf + palpha(fp16)
// + hw gather + fma only. [R8 structure: best measured.]
template<int H, bool ELU_ACT>
__global__ void k_agg(const __half* __restrict__ hw, const _Float16* __restrict__ palpha,
                      const float* __restrict__ alpha_s, const float* __restrict__ alpha_d,
                      const int* __restrict__ rstart, const int* __restrict__ rend,
                      const unsigned int* __restrict__ ebuf,
                      const float* __restrict__ bias, __half* __restrict__ hout, int n){
  int node = (blockIdx.x * blockDim.x + threadIdx.x) >> 6;
  int lane = threadIdx.x & 63;
  int g = lane >> 3, jj = lane & 7;
  if (node >= n) return;
  int hidx = (jj * H) >> 3;                // head of channels 8jj..8jj+7
  int start = rstart[node], end = rend[node];
  float acc[8] = {0.f,0.f,0.f,0.f,0.f,0.f,0.f,0.f};
  float psum = 0.f;
  if (g == 0){                             // self loop (group 0 only)
    float a = alpha_s[node * H + hidx] + alpha_d[node * H + hidx];
    a = a > 0.f ? a : 0.2f * a;
    float p = __expf(a);
    psum = p;
    float4 rv = *(const float4*)(hw + (size_t)node * 64 + jj * 8);
    const __half2* hp = (const __half2*)&rv;
    #pragma unroll
    for (int k = 0; k < 4; ++k){
      float2 f = __half22float2(hp[k]);
      acc[2 * k] = p * f.x; acc[2 * k + 1] = p * f.y;
    }
  }
  int i = start + g;
  for (; i + 8 < end; i += 16){
    unsigned int e0 = ebuf[i], e1 = ebuf[i + 8];
    int s0 = e0 & 0x1FFFF, s1 = e1 & 0x1FFFF;
    float p0 = (float)palpha[(size_t)i * H + hidx];
    float p1 = (float)palpha[(size_t)(i + 8) * H + hidx];
    float4 r0 = *(const float4*)(hw + (size_t)s0 * 64 + jj * 8);
    float4 r1 = *(const float4*)(hw + (size_t)s1 * 64 + jj * 8);
    const __half2* h0 = (const __half2*)&r0;
    const __half2* h1 = (const __half2*)&r1;
    psum += p0 + p1;
    #pragma unroll
    for (int k = 0; k < 4; ++k){
      float2 f0 = __half22float2(h0[k]);
      float2 f1 = __half22float2(h1[k]);
      acc[2 * k]     = fmaf(p0, f0.x, fmaf(p1, f1.x, acc[2 * k]));
      acc[2 * k + 1] = fmaf(p0, f0.y, fmaf(p1, f1.y, acc[2 * k + 1]));
    }
  }
  if (i < end){
    unsigned int en = ebuf[i];
    int s = en & 0x1FFFF;
    float p = (float)palpha[(size_t)i * H + hidx];
    float4 rv = *(const float4*)(hw + (size_t)s * 64 + jj * 8);
    const __half2* hp = (const __half2*)&rv;
    psum += p;
    #pragma unroll
    for (int k = 0; k < 4; ++k){
      float2 f = __half22float2(hp[k]);
      acc[2 * k]     = fmaf(p, f.x, acc[2 * k]);
      acc[2 * k + 1] = fmaf(p, f.y, acc[2 * k + 1]);
    }
  }
  #pragma unroll
  for (int off = 8; off < 64; off <<= 1){
    psum += __shfl_xor(psum, off);
    #pragma unroll
    for (int k = 0; k < 8; ++k) acc[k] += __shfl_xor(acc[k], off);
  }
  if (g == 0){
    float inv = 1.f / (psum + 1e-16f);
    float4 bv0 = ((const float4*)bias)[2 * jj];
    float4 bv1 = ((const float4*)bias)[2 * jj + 1];
    float o[8];
    o[0] = fmaf(acc[0], inv, bv0.x); o[1] = fmaf(acc[1], inv, bv0.y);
    o[2] = fmaf(acc[2], inv, bv0.z); o[3] = fmaf(acc[3], inv, bv0.w);
    o[4] = fmaf(acc[4], inv, bv1.x); o[5] = fmaf(acc[5], inv, bv1.y);
    o[6] = fmaf(acc[6], inv, bv1.z); o[7] = fmaf(acc[7], inv, bv1.w);
    if (ELU_ACT){
      #pragma unroll
      for (int k = 0; k < 8; ++k) o[k] = o[k] > 0.f ? o[k] : (__expf(o[k]) - 1.f);
    }
    half8_t hv;
    #pragma unroll
    for (int k = 0; k < 8; ++k) hv[k] = (_Float16)o[k];
    *(half8_t*)(hout + (size_t)node * 64 + jj * 8) = hv;
  }
}

// Fused heads GEMMs over h2 (fp16): P1/P2 fp16 + node head, 6 MFMAs/wave-tile.
__global__ __launch_bounds__(256) void k_heads_mfma(
    const __half* __restrict__ h, const float* __restrict__ eoW1,
    const float* __restrict__ noW1, const float* __restrict__ nob1,
    const float* __restrict__ noW2, const float* __restrict__ nob2,
    __half* __restrict__ P1, __half* __restrict__ P2,
    float* __restrict__ outN, int n){
  __shared__ float redP[4][16][2];
  int t = threadIdx.x;
  int lane = t & 63, wave = t >> 6;
  int l15 = lane & 15, quad = lane >> 4;
  int ch = wave * 16 + l15;
  half8_t bP1a, bP1b, bP2a, bP2b, bNa, bNb;
  #pragma unroll
  for (int j = 0; j < 8; ++j){
    int k0 = quad * 8 + j, k1 = k0 + 32;
    bP1a[j] = (_Float16)eoW1[k0 * 64 + ch];
    bP1b[j] = (_Float16)eoW1[k1 * 64 + ch];
    bP2a[j] = (_Float16)eoW1[(k0 + 64) * 64 + ch];
    bP2b[j] = (_Float16)eoW1[(k1 + 64) * 64 + ch];
    bNa[j]  = (_Float16)noW1[k0 * 64 + ch];
    bNb[j]  = (_Float16)noW1[k1 * 64 + ch];
  }
  float b1v = nob1[ch];
  float w20 = noW2[ch * 2 + 0], w21 = noW2[ch * 2 + 1];
  float b20 = nob2[0], b21 = nob2[1];
  int base = blockIdx.x * 64;
  for (int it = 0; it < 4; ++it){
    int tb = base + it * 16;
    if (tb >= n) break;
    int arn = tb + l15; if (arn >= n) arn = n - 1;
    const __half* arow = h + (size_t)arn * 64 + quad * 8;
    half8_t a0 = *(const half8_t*)arow;
    half8_t a1 = *(const half8_t*)(arow + 32);
    floatx4 ac1 = {0.f,0.f,0.f,0.f}, ac2 = {0.f,0.f,0.f,0.f}, acN = {0.f,0.f,0.f,0.f};
    ac1 = __builtin_amdgcn_mfma_f32_16x16x32_f16(a0, bP1a, ac1, 0, 0, 0);
    ac1 = __builtin_amdgcn_mfma_f32_16x16x32_f16(a1, bP1b, ac1, 0, 0, 0);
    ac2 = __builtin_amdgcn_mfma_f32_16x16x32_f16(a0, bP2a, ac2, 0, 0, 0);
    ac2 = __builtin_amdgcn_mfma_f32_16x16x32_f16(a1, bP2b, ac2, 0, 0, 0);
    acN = __builtin_amdgcn_mfma_f32_16x16x32_f16(a0, bNa, acN, 0, 0, 0);
    acN = __builtin_amdgcn_mfma_f32_16x16x32_f16(a1, bNb, acN, 0, 0, 0);
    float p0[4], p1[4];
    #pragma unroll
    for (int r = 0; r < 4; ++r){
      int node = tb + quad * 4 + r;
      if (node < n){
        P1[(size_t)node * 64 + ch] = __float2half(ac1[r]);
        P2[(size_t)node * 64 + ch] = __float2half(ac2[r]);
      }
      float v = acN[r] + b1v;
      v = v > 0.f ? v : 0.01f * v;
      p0[r] = v * w20;
      p1[r] = v * w21;
      #pragma unroll
      for (int off = 1; off < 16; off <<= 1){
        p0[r] += __shfl_xor(p0[r], off);
        p1[r] += __shfl_xor(p1[r], off);
      }
    }
    if (l15 == 0){
      #pragma unroll
      for (int r = 0; r < 4; ++r){
        redP[wave][quad * 4 + r][0] = p0[r];
        redP[wave][quad * 4 + r][1] = p1[r];
      }
    }
    __syncthreads();
    if (t < 16 && tb + t < n){
      float s0 = redP[0][t][0] + redP[1][t][0] + redP[2][t][0] + redP[3][t][0];
      float s1 = redP[0][t][1] + redP[1][t][1] + redP[2][t][1] + redP[3][t][1];
      outN[(size_t)(tb + t) * 2 + 0] = tanhf(s0 + b20);
      outN[(size_t)(tb + t) * 2 + 1] = tanhf(s1 + b21);
    }
    __syncthreads();
  }
}

// 16 edges per wave-iteration: 8 groups of 8 lanes, each group handles edges
// e and e+8 (2x unroll -> 32 gathers in flight per wave).
__global__ void k_edge_head(const __half* __restrict__ P1h, const __half* __restrict__ P2h,
                            const int* __restrict__ src, const int* __restrict__ dst,
                            const float* __restrict__ eattr, const float* __restrict__ eoW1,
                            const float* __restrict__ b1, const float* __restrict__ W2,
                            const float* __restrict__ b2, float* __restrict__ out, int E){
  int lane = threadIdx.x & 63;
  int jj = lane & 7, q = lane >> 3;
  int wid = (blockIdx.x * blockDim.x + threadIdx.x) >> 6;
  int nw = (gridDim.x * blockDim.x) >> 6;

  const float4* rAq = (const float4*)(eoW1 + 8192);
  const float4* rBq = (const float4*)(eoW1 + 8256);
  const float4* b1q = (const float4*)b1;
  const float4* w2q = (const float4*)W2;
  float4 tA0 = rAq[2 * jj], tA1 = rAq[2 * jj + 1];
  float4 tB0 = rBq[2 * jj], tB1 = rBq[2 * jj + 1];
  float4 tb0 = b1q[2 * jj], tb1 = b1q[2 * jj + 1];
  float4 tw0 = w2q[2 * jj], tw1 = w2q[2 * jj + 1];
  float ra[8] = {tA0.x, tA0.y, tA0.z, tA0.w, tA1.x, tA1.y, tA1.z, tA1.w};
  float rb[8] = {tB0.x, tB0.y, tB0.z, tB0.w, tB1.x, tB1.y, tB1.z, tB1.w};
  float bb[8] = {tb0.x, tb0.y, tb0.z, tb0.w, tb1.x, tb1.y, tb1.z, tb1.w};
  float w2[8] = {tw0.x, tw0.y, tw0.z, tw0.w, tw1.x, tw1.y, tw1.z, tw1.w};
  float b2v = b2[0];

  const float4* P1q = (const float4*)P1h;
  const float4* P2q = (const float4*)P2h;
  const float2* eav = (const float2*)eattr;

  int groups = (E + 15) >> 4;
  for (int g = wid; g < groups; g += nw){
    int e0 = g * 16 + q, e1 = e0 + 8;
    bool act0 = (e0 < E), act1 = (e1 < E);
    float p0 = 0.f, p1 = 0.f;
    if (act0){
      int s = src[e0], d = dst[e0];
      float2 ea = eav[e0];
      float4 g1 = P1q[(size_t)s * 8 + jj];
      float4 g2 = P2q[(size_t)d * 8 + jj];
      const __half2* h1 = (const __half2*)&g1;
      const __half2* h2 = (const __half2*)&g2;
      #pragma unroll
      for (int k = 0; k < 4; ++k){
        float2 u = __half22float2(h1[k]);
        float2 w = __half22float2(h2[k]);
        float ta = u.x + w.x + bb[2 * k];
        float tb = u.y + w.y + bb[2 * k + 1];
        ta = fmaf(ea.x, ra[2 * k], fmaf(ea.y, rb[2 * k], ta));
        tb = fmaf(ea.x, ra[2 * k + 1], fmaf(ea.y, rb[2 * k + 1], tb));
        ta = ta > 0.f ? ta : 0.01f * ta;
        tb = tb > 0.f ? tb : 0.01f * tb;
        p0 = fmaf(ta, w2[2 * k], fmaf(tb, w2[2 * k + 1], p0));
      }
    }
    if (act1){
      int s = src[e1], d = dst[e1];
      float2 ea = eav[e1];
      float4 g1 = P1q[(size_t)s * 8 + jj];
      float4 g2 = P2q[(size_t)d * 8 + jj];
      const __half2* h1 = (const __half2*)&g1;
      const __half2* h2 = (const __half2*)&g2;
      #pragma unroll
      for (int k = 0; k < 4; ++k){
        float2 u = __half22float2(h1[k]);
        float2 w = __half22float2(h2[k]);
        float ta = u.x + w.x + bb[2 * k];
        float tb = u.y + w.y + bb[2 * k + 1];
        ta = fmaf(ea.x, ra[2 * k], fmaf(ea.y, rb[2 * k], ta));
        tb = fmaf(ea.x, ra[2 * k + 1], fmaf(ea.y, rb[2 * k + 1], tb));
        ta = ta > 0.f ? ta : 0.01f * ta;
        tb = tb > 0.f ? tb : 0.01f * tb;
        p1 = fmaf(ta, w2[2 * k], fmaf(tb, w2[2 * k + 1], p1));
      }
    }
    #pragma unroll
    for (int off = 1; off < 8; off <<= 1){
      p0 += __shfl_xor(p0, off);
      p1 += __shfl_xor(p1, off);
    }
    if (jj == 0){
      if (act0) out[e0] = tanhf(p0 + b2v);
      if (act1) out[e1] = tanhf(p1 + b2v);
    }
  }
}

extern "C" void kernel_launch(void* const* d_in, const int* in_sizes, int n_in,
                              void* d_out, int out_size, void* d_ws, size_t ws_size,
                              hipStream_t stream){
  const float* x    = (const float*)d_in[0];
  const int*   eidx = (const int*)  d_in[1];
  const float* ea   = (const float*)d_in[2];
  const float* encW = (const float*)d_in[3];
  const float* encb = (const float*)d_in[4];
  const float* g1W  = (const float*)d_in[5];
  const float* g1as = (const float*)d_in[6];
  const float* g1ad = (const float*)d_in[7];
  const float* g1b  = (const float*)d_in[8];
  const float* g2W  = (const float*)d_in[9];
  const float* g2as = (const float*)d_in[10];
  const float* g2ad = (const float*)d_in[11];
  const float* g2b  = (const float*)d_in[12];
  const float* noW1 = (const float*)d_in[13];
  const float* nob1 = (const float*)d_in[14];
  const float* noW2 = (const float*)d_in[15];
  const float* nob2 = (const float*)d_in[16];
  const float* eoW1 = (const float*)d_in[17];
  const float* eob1 = (const float*)d_in[18];
  const float* eoW2 = (const float*)d_in[19];
  const float* eob2 = (const float*)d_in[20];

  const int N = in_sizes[0] / 2;
  const int E = in_sizes[1] / 2;
  const int* src = eidx;
  const int* dst = eidx + E;

  const int NB = (N + 127) >> 7;         // buckets of 128 nodes (<= 800)
  int avg = (E + NB - 1) / NB;
  int cap = avg + avg / 4 + 64;          // ~25% headroom
  if (cap > 2700) cap = 2700;            // LDS limit in k_bucket_build

  // workspace layout
  char* ws = (char*)d_ws;
  size_t off = 0;
  auto alloc = [&](size_t bytes) -> void* {
    void* p = ws + off;
    off = (off + bytes + 255) & ~(size_t)255;
    return p;
  };
  __half* bufA  = (__half*)alloc((size_t)N * 64 * 2);   // h1 -> h2 (fp16)
  __half* bufH  = (__half*)alloc((size_t)N * 64 * 2);   // hw1 -> hw2
  __half* P1h   = (__half*)alloc((size_t)N * 64 * 2);
  __half* P2h   = (__half*)alloc((size_t)N * 64 * 2);
  float*  as    = (float*) alloc((size_t)N * 4 * 4);
  float*  ad    = (float*) alloc((size_t)N * 4 * 4);
  int* rstart   = (int*)   alloc((size_t)N * 4);
  int* rend     = (int*)   alloc((size_t)N * 4);
  unsigned int* ebuf = (unsigned int*)alloc((size_t)NB * cap * 4);   // packed entries
  _Float16* palphaB = (_Float16*)alloc((size_t)NB * cap * 8);        // layer1 h4 / layer2 h1
  int* cursor   = (int*)   alloc((size_t)NB * 4);
  float* Mc     = (float*) alloc(192 * 4);              // fused enc@g1W [2,64]+[64]

  // ---- CSR build phase 1 (+ tiny enc@g1W precompute in block 0) ----
  hipMemsetAsync(cursor, 0, (size_t)NB * 4, stream);
  k_scatter<<<(E + 2047) / 2048, 256, 0, stream>>>(src, dst, E, NB, cap, cursor, ebuf,
                                                   encW, encb, g1W, Mc);
  // ---- layer-1 hw + alphas ----
  k_fuse1<<<(N * 64 + 255) / 256, 256, 0, stream>>>(x, Mc, g1as, g1ad, bufH, as, ad, N);
  // ---- CSR build phase 2 + layer-1 edge numerators ----
  k_bucket_build<<<NB, 256, 0, stream>>>(cursor, cap, N, ebuf, rstart, rend,
                                         as, ad, (half4_t*)palphaB);
  // ---- layer-1 aggregation + ELU ----
  k_agg<4, true><<<(N + 3) / 4, 256, 0, stream>>>(bufH, palphaB, as, ad,
                                                  rstart, rend, ebuf, g1b, bufA, N);
  // ---- GAT layer 2 ----
  k_hw_mfma<<<(N + 63) / 64, 256, 0, stream>>>(bufA, g2W, g2as, g2ad, bufH, as, ad, N);
  k_palpha1<<<NB * 4, 256, 0, stream>>>(cursor, cap, ebuf, as, ad, palphaB);
  k_agg<1, false><<<(N + 3) / 4, 256, 0, stream>>>(bufH, palphaB, as, ad,
                                                   rstart, rend, ebuf, g2b, bufA, N);
  // ---- heads (fused P1/P2 + node head) ----
  float* out = (float*)d_out;
  k_heads_mfma<<<(N + 63) / 64, 256, 0, stream>>>(bufA, eoW1, noW1, nob1, noW2, nob2,
                                                  P1h, P2h, out + E, N);
  k_edge_head<<<2048, 256, 0, stream>>>(P1h, P2h, src, dst, ea,
                                        eoW1, eob1, eoW2, eob2, out, E);
}

// Round 14
// 378.244 us; speedup vs baseline: 1.0242x; 1.0242x over previous
//
#include <hip/hip_runtime.h>
#include <hip/hip_fp16.h>
#include <math.h>

// ---------------------------------------------------------------------------
// GAT model forward. N=100k nodes, E=1.6M edges, HID=64.
// R13 changes vs R12 (plateau ~384-387us):
//  - k_fuse1 merged into k_scatter (independent work; Mc recomputed per-block
//    from L2-resident g1W; fuse1's streaming rides the latency-bound scatter)
//  - layer-2 palpha inlined into k_agg<1>: dst alpha is the wave's node, src
//    alpha is a 4B gather from the 400KB L2-resident as[] table -> k_palpha1
//    launch + 9.6MB streams eliminated. 9 -> 8 dispatches.
//  - gather kernels otherwise untouched (edge head at structural replication
//    floor; R8 agg structure = proven local optimum).
// ---------------------------------------------------------------------------

typedef _Float16 half8_t __attribute__((ext_vector_type(8)));
typedef _Float16 half4_t __attribute__((ext_vector_type(4)));
typedef float floatx4 __attribute__((ext_vector_type(4)));

// Phase 1: bucket edges by dst>>7 (rank trick: count-pass atomic return IS the
// rank). Then grid-stride fuse1 tail: hw1 = fp16(x@Mc+c), H=4 alphas.
__global__ void k_scatter_fuse(const int* __restrict__ src, const int* __restrict__ dst,
                               int E, int NB, int cap, int* cursor,
                               unsigned int* __restrict__ ebuf,
                               const float* __restrict__ x,
                               const float* __restrict__ encW, const float* __restrict__ encb,
                               const float* __restrict__ g1W,
                               const float* __restrict__ g1as, const float* __restrict__ g1ad,
                               __half* __restrict__ hw, float* __restrict__ alpha_s,
                               float* __restrict__ alpha_d, int n){
  __shared__ int hist[800];
  __shared__ int base[800];
  __shared__ float McS[192];
  int t = threadIdx.x;                  // blockDim = 256
  if (t < 64){                          // per-block Mc (g1W is L2-resident)
    float m0 = 0.f, m1 = 0.f, cc = 0.f;
    for (int k = 0; k < 64; ++k){
      float g = g1W[k * 64 + t];
      m0 = fmaf(encW[k], g, m0);
      m1 = fmaf(encW[64 + k], g, m1);
      cc = fmaf(encb[k], g, cc);
    }
    McS[t] = m0; McS[64 + t] = m1; McS[128 + t] = cc;
  }
  for (int i = t; i < NB; i += 256) hist[i] = 0;
  __syncthreads();
  int cbase = blockIdx.x * 2048;
  int sv[8], bk[8], dl[8], rk[8];
  #pragma unroll
  for (int i = 0; i < 8; ++i){
    int e = cbase + i * 256 + t;
    if (e < E){
      int d = dst[e];
      sv[i] = src[e]; bk[i] = d >> 7; dl[i] = d & 127;
      rk[i] = atomicAdd(&hist[bk[i]], 1);   // rank within (block,bucket)
    } else bk[i] = -1;
  }
  __syncthreads();
  for (int i = t; i < NB; i += 256){
    int c = hist[i];
    base[i] = (c > 0) ? (i * cap + atomicAdd(&cursor[i], c)) : 0;
  }
  __syncthreads();
  #pragma unroll
  for (int i = 0; i < 8; ++i){
    if (bk[i] >= 0){
      int p = base[bk[i]] + rk[i];
      if (p < (bk[i] + 1) * cap)        // overflow guard (never fires in practice)
        ebuf[p] = (unsigned)sv[i] | ((unsigned)dl[i] << 17);
    }
  }
  // ---- fuse1 tail: grid-stride over n*64 channels ----
  int total = n * 64;
  int lane = t & 63;
  for (int idx = blockIdx.x * 256 + t; idx < total; idx += gridDim.x * 256){
    int node = idx >> 6;                // j == lane (idx base multiple of 64)
    float acc = fmaf(x[node * 2 + 0], McS[lane],
                fmaf(x[node * 2 + 1], McS[64 + lane], McS[128 + lane]));
    hw[idx] = __float2half(acc);
    float ps = acc * g1as[lane];
    float pd = acc * g1ad[lane];
    #pragma unroll
    for (int off = 1; off < 16; off <<= 1){
      ps += __shfl_xor(ps, off);
      pd += __shfl_xor(pd, off);
    }
    if ((lane & 15) == 0){
      int h = lane >> 4;
      alpha_s[node * 4 + h] = ps;
      alpha_d[node * 4 + h] = pd;
    }
  }
}

// Phase 2: one block (256 thr) per 128-node bucket. Sort in LDS ->
// rstart/rend + dst-sorted packed ebuf, AND emit layer-1 palpha4 (fp16).
__global__ void k_bucket_build(const int* __restrict__ cursor, int cap, int N,
                               unsigned int* ebuf, int* __restrict__ rstart,
                               int* __restrict__ rend,
                               const float* __restrict__ as4,
                               const float* __restrict__ ad4,
                               half4_t* __restrict__ palpha4){
  __shared__ unsigned int ent[2700];
  __shared__ unsigned short rank[2700];
  __shared__ int cnts[128];
  __shared__ int aux[128];
  int b = blockIdx.x, t = threadIdx.x;  // blockDim = 256
  int base = b * cap;
  int cnt = cursor[b];
  if (cnt > cap) cnt = cap;
  for (int i = t; i < cnt; i += 256) ent[i] = ebuf[base + i];
  if (t < 128) cnts[t] = 0;
  __syncthreads();
  for (int i = t; i < cnt; i += 256)
    rank[i] = (unsigned short)atomicAdd(&cnts[ent[i] >> 17], 1);
  __syncthreads();
  int v = 0;
  if (t < 128){ v = cnts[t]; aux[t] = v; }
  __syncthreads();
  for (int off = 1; off < 128; off <<= 1){
    int x = 0;
    if (t < 128 && t >= off) x = aux[t - off];
    __syncthreads();
    if (t < 128) aux[t] += x;
    __syncthreads();
  }
  if (t < 128){
    int incl = aux[t];
    int node = (b << 7) + t;
    if (node < N){ rstart[node] = base + incl - v; rend[node] = base + incl; }
    cnts[t] = incl - v;                 // per-node segment start (no atomics)
  }
  __syncthreads();
  for (int i = t; i < cnt; i += 256){
    unsigned int en = ent[i];
    int dl = en >> 17;
    int s = en & 0x1FFFFu;
    int pos = cnts[dl] + (int)rank[i];
    ebuf[base + pos] = en;              // keep packed (src|dl<<17)
    int d = (b << 7) + dl;
    float4 sv = ((const float4*)as4)[s];
    float4 dv = ((const float4*)ad4)[d];
    float a0 = sv.x + dv.x, a1 = sv.y + dv.y, a2 = sv.z + dv.z, a3 = sv.w + dv.w;
    a0 = a0 > 0.f ? a0 : 0.2f * a0;
    a1 = a1 > 0.f ? a1 : 0.2f * a1;
    a2 = a2 > 0.f ? a2 : 0.2f * a2;
    a3 = a3 > 0.f ? a3 : 0.2f * a3;
    half4_t pv = {(_Float16)__expf(a0), (_Float16)__expf(a1),
                  (_Float16)__expf(a2), (_Float16)__expf(a3)};
    palpha4[base + pos] = pv;
  }
}

// MFMA GEMM: hw2 = fp16(h1 @ g2W); alpha_s/d (H=1) = rowsum(hw2 * a_{s,d}).
__global__ __launch_bounds__(256) void k_hw_mfma(
    const __half* __restrict__ hin, const float* __restrict__ W,
    const float* __restrict__ a_s, const float* __restrict__ a_d,
    __half* __restrict__ hw, float* __restrict__ alpha_s,
    float* __restrict__ alpha_d, int n){
  __shared__ float redS[4][16];
  __shared__ float redD[4][16];
  int t = threadIdx.x;
  int lane = t & 63, wave = t >> 6;
  int l15 = lane & 15, quad = lane >> 4;
  int ch = wave * 16 + l15;
  half8_t b0, b1;
  #pragma unroll
  for (int j = 0; j < 8; ++j){
    b0[j] = (_Float16)W[(quad * 8 + j) * 64 + ch];
    b1[j] = (_Float16)W[(quad * 8 + j + 32) * 64 + ch];
  }
  float asv = a_s[ch], adv = a_d[ch];
  int base = blockIdx.x * 64;
  for (int it = 0; it < 4; ++it){
    int tb = base + it * 16;
    if (tb >= n) break;
    int arn = tb + l15; if (arn >= n) arn = n - 1;
    const __half* arow = hin + (size_t)arn * 64 + quad * 8;
    half8_t a0 = *(const half8_t*)arow;
    half8_t a1 = *(const half8_t*)(arow + 32);
    floatx4 acc = {0.f, 0.f, 0.f, 0.f};
    acc = __builtin_amdgcn_mfma_f32_16x16x32_f16(a0, b0, acc, 0, 0, 0);
    acc = __builtin_amdgcn_mfma_f32_16x16x32_f16(a1, b1, acc, 0, 0, 0);
    float ps[4], pd[4];
    #pragma unroll
    for (int r = 0; r < 4; ++r){
      int node = tb + quad * 4 + r;
      if (node < n) hw[(size_t)node * 64 + ch] = __float2half(acc[r]);
      ps[r] = acc[r] * asv;
      pd[r] = acc[r] * adv;
      #pragma unroll
      for (int off = 1; off < 16; off <<= 1){
        ps[r] += __shfl_xor(ps[r], off);
        pd[r] += __shfl_xor(pd[r], off);
      }
    }
    if (l15 == 0){
      #pragma unroll
      for (int r = 0; r < 4; ++r){
        redS[wave][quad * 4 + r] = ps[r];
        redD[wave][quad * 4 + r] = pd[r];
      }
    }
    __syncthreads();
    if (t < 16 && tb + t < n){
      alpha_s[tb + t] = redS[0][t] + redS[1][t] + redS[2][t] + redS[3][t];
      alpha_d[tb + t] = redD[0][t] + redD[1][t] + redD[2][t] + redD[3][t];
    }
    __syncthreads();
  }
}

// Wave = 1 destination node, 8 edge-groups x 8 lanes; lane jj owns channels
// 8jj..8jj+7 (one 16B fp16 load per edge). [R8 structure: best measured.]
// INLINE_A (H=1 only): numerator computed in-loop from L2-resident as[] +
// the wave's own ad[node] (no palpha array/launch needed).
template<int H, bool ELU_ACT, bool INLINE_A>
__global__ void k_agg(const __half* __restrict__ hw, const _Float16* __restrict__ palpha,
                      const float* __restrict__ alpha_s, const float* __restrict__ alpha_d,
                      const int* __restrict__ rstart, const int* __restrict__ rend,
                      const unsigned int* __restrict__ ebuf,
                      const float* __restrict__ bias, __half* __restrict__ hout, int n){
  int node = (blockIdx.x * blockDim.x + threadIdx.x) >> 6;
  int lane = threadIdx.x & 63;
  int g = lane >> 3, jj = lane & 7;
  if (node >= n) return;
  int hidx = (jj * H) >> 3;                // head of channels 8jj..8jj+7
  int start = rstart[node], end = rend[node];
  float adn = INLINE_A ? alpha_d[node] : 0.f;
  float acc[8] = {0.f,0.f,0.f,0.f,0.f,0.f,0.f,0.f};
  float psum = 0.f;
  if (g == 0){                             // self loop (group 0 only)
    float a = alpha_s[node * H + hidx] + alpha_d[node * H + hidx];
    a = a > 0.f ? a : 0.2f * a;
    float p = __expf(a);
    psum = p;
    float4 rv = *(const float4*)(hw + (size_t)node * 64 + jj * 8);
    const __half2* hp = (const __half2*)&rv;
    #pragma unroll
    for (int k = 0; k < 4; ++k){
      float2 f = __half22float2(hp[k]);
      acc[2 * k] = p * f.x; acc[2 * k + 1] = p * f.y;
    }
  }
  int i = start + g;
  for (; i + 8 < end; i += 16){
    unsigned int e0 = ebuf[i], e1 = ebuf[i + 8];
    int s0 = e0 & 0x1FFFF, s1 = e1 & 0x1FFFF;
    float p0, p1;
    if (INLINE_A){
      float a0 = alpha_s[s0] + adn;
      float a1 = alpha_s[s1] + adn;
      a0 = a0 > 0.f ? a0 : 0.2f * a0;
      a1 = a1 > 0.f ? a1 : 0.2f * a1;
      p0 = __expf(a0); p1 = __expf(a1);
    } else {
      p0 = (float)palpha[(size_t)i * H + hidx];
      p1 = (float)palpha[(size_t)(i + 8) * H + hidx];
    }
    float4 r0 = *(const float4*)(hw + (size_t)s0 * 64 + jj * 8);
    float4 r1 = *(const float4*)(hw + (size_t)s1 * 64 + jj * 8);
    const __half2* h0 = (const __half2*)&r0;
    const __half2* h1 = (const __half2*)&r1;
    psum += p0 + p1;
    #pragma unroll
    for (int k = 0; k < 4; ++k){
      float2 f0 = __half22float2(h0[k]);
      float2 f1 = __half22float2(h1[k]);
      acc[2 * k]     = fmaf(p0, f0.x, fmaf(p1, f1.x, acc[2 * k]));
      acc[2 * k + 1] = fmaf(p0, f0.y, fmaf(p1, f1.y, acc[2 * k + 1]));
    }
  }
  if (i < end){
    unsigned int en = ebuf[i];
    int s = en & 0x1FFFF;
    float p;
    if (INLINE_A){
      float a = alpha_s[s] + adn;
      a = a > 0.f ? a : 0.2f * a;
      p = __expf(a);
    } else {
      p = (float)palpha[(size_t)i * H + hidx];
    }
    float4 rv = *(const float4*)(hw + (size_t)s * 64 + jj * 8);
    const __half2* hp = (const __half2*)&rv;
    psum += p;
    #pragma unroll
    for (int k = 0; k < 4; ++k){
      float2 f = __half22float2(hp[k]);
      acc[2 * k]     = fmaf(p, f.x, acc[2 * k]);
      acc[2 * k + 1] = fmaf(p, f.y, acc[2 * k + 1]);
    }
  }
  #pragma unroll
  for (int off = 8; off < 64; off <<= 1){
    psum += __shfl_xor(psum, off);
    #pragma unroll
    for (int k = 0; k < 8; ++k) acc[k] += __shfl_xor(acc[k], off);
  }
  if (g == 0){
    float inv = 1.f / (psum + 1e-16f);
    float4 bv0 = ((const float4*)bias)[2 * jj];
    float4 bv1 = ((const float4*)bias)[2 * jj + 1];
    float o[8];
    o[0] = fmaf(acc[0], inv, bv0.x); o[1] = fmaf(acc[1], inv, bv0.y);
    o[2] = fmaf(acc[2], inv, bv0.z); o[3] = fmaf(acc[3], inv, bv0.w);
    o[4] = fmaf(acc[4], inv, bv1.x); o[5] = fmaf(acc[5], inv, bv1.y);
    o[6] = fmaf(acc[6], inv, bv1.z); o[7] = fmaf(acc[7], inv, bv1.w);
    if (ELU_ACT){
      #pragma unroll
      for (int k = 0; k < 8; ++k) o[k] = o[k] > 0.f ? o[k] : (__expf(o[k]) - 1.f);
    }
    half8_t hv;
    #pragma unroll
    for (int k = 0; k < 8; ++k) hv[k] = (_Float16)o[k];
    *(half8_t*)(hout + (size_t)node * 64 + jj * 8) = hv;
  }
}

// Fused heads GEMMs over h2 (fp16): P1/P2 fp16 + node head, 6 MFMAs/wave-tile.
__global__ __launch_bounds__(256) void k_heads_mfma(
    const __half* __restrict__ h, const float* __restrict__ eoW1,
    const float* __restrict__ noW1, const float* __restrict__ nob1,
    const float* __restrict__ noW2, const float* __restrict__ nob2,
    __half* __restrict__ P1, __half* __restrict__ P2,
    float* __restrict__ outN, int n){
  __shared__ float redP[4][16][2];
  int t = threadIdx.x;
  int lane = t & 63, wave = t >> 6;
  int l15 = lane & 15, quad = lane >> 4;
  int ch = wave * 16 + l15;
  half8_t bP1a, bP1b, bP2a, bP2b, bNa, bNb;
  #pragma unroll
  for (int j = 0; j < 8; ++j){
    int k0 = quad * 8 + j, k1 = k0 + 32;
    bP1a[j] = (_Float16)eoW1[k0 * 64 + ch];
    bP1b[j] = (_Float16)eoW1[k1 * 64 + ch];
    bP2a[j] = (_Float16)eoW1[(k0 + 64) * 64 + ch];
    bP2b[j] = (_Float16)eoW1[(k1 + 64) * 64 + ch];
    bNa[j]  = (_Float16)noW1[k0 * 64 + ch];
    bNb[j]  = (_Float16)noW1[k1 * 64 + ch];
  }
  float b1v = nob1[ch];
  float w20 = noW2[ch * 2 + 0], w21 = noW2[ch * 2 + 1];
  float b20 = nob2[0], b21 = nob2[1];
  int base = blockIdx.x * 64;
  for (int it = 0; it < 4; ++it){
    int tb = base + it * 16;
    if (tb >= n) break;
    int arn = tb + l15; if (arn >= n) arn = n - 1;
    const __half* arow = h + (size_t)arn * 64 + quad * 8;
    half8_t a0 = *(const half8_t*)arow;
    half8_t a1 = *(const half8_t*)(arow + 32);
    floatx4 ac1 = {0.f,0.f,0.f,0.f}, ac2 = {0.f,0.f,0.f,0.f}, acN = {0.f,0.f,0.f,0.f};
    ac1 = __builtin_amdgcn_mfma_f32_16x16x32_f16(a0, bP1a, ac1, 0, 0, 0);
    ac1 = __builtin_amdgcn_mfma_f32_16x16x32_f16(a1, bP1b, ac1, 0, 0, 0);
    ac2 = __builtin_amdgcn_mfma_f32_16x16x32_f16(a0, bP2a, ac2, 0, 0, 0);
    ac2 = __builtin_amdgcn_mfma_f32_16x16x32_f16(a1, bP2b, ac2, 0, 0, 0);
    acN = __builtin_amdgcn_mfma_f32_16x16x32_f16(a0, bNa, acN, 0, 0, 0);
    acN = __builtin_amdgcn_mfma_f32_16x16x32_f16(a1, bNb, acN, 0, 0, 0);
    float p0[4], p1[4];
    #pragma unroll
    for (int r = 0; r < 4; ++r){
      int node = tb + quad * 4 + r;
      if (node < n){
        P1[(size_t)node * 64 + ch] = __float2half(ac1[r]);
        P2[(size_t)node * 64 + ch] = __float2half(ac2[r]);
      }
      float v = acN[r] + b1v;
      v = v > 0.f ? v : 0.01f * v;
      p0[r] = v * w20;
      p1[r] = v * w21;
      #pragma unroll
      for (int off = 1; off < 16; off <<= 1){
        p0[r] += __shfl_xor(p0[r], off);
        p1[r] += __shfl_xor(p1[r], off);
      }
    }
    if (l15 == 0){
      #pragma unroll
      for (int r = 0; r < 4; ++r){
        redP[wave][quad * 4 + r][0] = p0[r];
        redP[wave][quad * 4 + r][1] = p1[r];
      }
    }
    __syncthreads();
    if (t < 16 && tb + t < n){
      float s0 = redP[0][t][0] + redP[1][t][0] + redP[2][t][0] + redP[3][t][0];
      float s1 = redP[0][t][1] + redP[1][t][1] + redP[2][t][1] + redP[3][t][1];
      outN[(size_t)(tb + t) * 2 + 0] = tanhf(s0 + b20);
      outN[(size_t)(tb + t) * 2 + 1] = tanhf(s1 + b21);
    }
    __syncthreads();
  }
}

// 16 edges per wave-iteration: 8 groups of 8 lanes, each group handles edges
// e and e+8 (2x unroll -> 32 gathers in flight per wave).
__global__ void k_edge_head(const __half* __restrict__ P1h, const __half* __restrict__ P2h,
                            const int* __restrict__ src, const int* __restrict__ dst,
                            const float* __restrict__ eattr, const float* __restrict__ eoW1,
                            const float* __restrict__ b1, const float* __restrict__ W2,
                            const float* __restrict__ b2, float* __restrict__ out, int E){
  int lane = threadIdx.x & 63;
  int jj = lane & 7, q = lane >> 3;
  int wid = (blockIdx.x * blockDim.x + threadIdx.x) >> 6;
  int nw = (gridDim.x * blockDim.x) >> 6;

  const float4* rAq = (const float4*)(eoW1 + 8192);
  const float4* rBq = (const float4*)(eoW1 + 8256);
  const float4* b1q = (const float4*)b1;
  const float4* w2q = (const float4*)W2;
  float4 tA0 = rAq[2 * jj], tA1 = rAq[2 * jj + 1];
  float4 tB0 = rBq[2 * jj], tB1 = rBq[2 * jj + 1];
  float4 tb0 = b1q[2 * jj], tb1 = b1q[2 * jj + 1];
  float4 tw0 = w2q[2 * jj], tw1 = w2q[2 * jj + 1];
  float ra[8] = {tA0.x, tA0.y, tA0.z, tA0.w, tA1.x, tA1.y, tA1.z, tA1.w};
  float rb[8] = {tB0.x, tB0.y, tB0.z, tB0.w, tB1.x, tB1.y, tB1.z, tB1.w};
  float bb[8] = {tb0.x, tb0.y, tb0.z, tb0.w, tb1.x, tb1.y, tb1.z, tb1.w};
  float w2[8] = {tw0.x, tw0.y, tw0.z, tw0.w, tw1.x, tw1.y, tw1.z, tw1.w};
  float b2v = b2[0];

  const float4* P1q = (const float4*)P1h;
  const float4* P2q = (const float4*)P2h;
  const float2* eav = (const float2*)eattr;

  int groups = (E + 15) >> 4;
  for (int g = wid; g < groups; g += nw){
    int e0 = g * 16 + q, e1 = e0 + 8;
    bool act0 = (e0 < E), act1 = (e1 < E);
    float p0 = 0.f, p1 = 0.f;
    if (act0){
      int s = src[e0], d = dst[e0];
      float2 ea = eav[e0];
      float4 g1 = P1q[(size_t)s * 8 + jj];
      float4 g2 = P2q[(size_t)d * 8 + jj];
      const __half2* h1 = (const __half2*)&g1;
      const __half2* h2 = (const __half2*)&g2;
      #pragma unroll
      for (int k = 0; k < 4; ++k){
        float2 u = __half22float2(h1[k]);
        float2 w = __half22float2(h2[k]);
        float ta = u.x + w.x + bb[2 * k];
        float tb = u.y + w.y + bb[2 * k + 1];
        ta = fmaf(ea.x, ra[2 * k], fmaf(ea.y, rb[2 * k], ta));
        tb = fmaf(ea.x, ra[2 * k + 1], fmaf(ea.y, rb[2 * k + 1], tb));
        ta = ta > 0.f ? ta : 0.01f * ta;
        tb = tb > 0.f ? tb : 0.01f * tb;
        p0 = fmaf(ta, w2[2 * k], fmaf(tb, w2[2 * k + 1], p0));
      }
    }
    if (act1){
      int s = src[e1], d = dst[e1];
      float2 ea = eav[e1];
      float4 g1 = P1q[(size_t)s * 8 + jj];
      float4 g2 = P2q[(size_t)d * 8 + jj];
      const __half2* h1 = (const __half2*)&g1;
      const __half2* h2 = (const __half2*)&g2;
      #pragma unroll
      for (int k = 0; k < 4; ++k){
        float2 u = __half22float2(h1[k]);
        float2 w = __half22float2(h2[k]);
        float ta = u.x + w.x + bb[2 * k];
        float tb = u.y + w.y + bb[2 * k + 1];
        ta = fmaf(ea.x, ra[2 * k], fmaf(ea.y, rb[2 * k], ta));
        tb = fmaf(ea.x, ra[2 * k + 1], fmaf(ea.y, rb[2 * k + 1], tb));
        ta = ta > 0.f ? ta : 0.01f * ta;
        tb = tb > 0.f ? tb : 0.01f * tb;
        p1 = fmaf(ta, w2[2 * k], fmaf(tb, w2[2 * k + 1], p1));
      }
    }
    #pragma unroll
    for (int off = 1; off < 8; off <<= 1){
      p0 += __shfl_xor(p0, off);
      p1 += __shfl_xor(p1, off);
    }
    if (jj == 0){
      if (act0) out[e0] = tanhf(p0 + b2v);
      if (act1) out[e1] = tanhf(p1 + b2v);
    }
  }
}

extern "C" void kernel_launch(void* const* d_in, const int* in_sizes, int n_in,
                              void* d_out, int out_size, void* d_ws, size_t ws_size,
                              hipStream_t stream){
  const float* x    = (const float*)d_in[0];
  const int*   eidx = (const int*)  d_in[1];
  const float* ea   = (const float*)d_in[2];
  const float* encW = (const float*)d_in[3];
  const float* encb = (const float*)d_in[4];
  const float* g1W  = (const float*)d_in[5];
  const float* g1as = (const float*)d_in[6];
  const float* g1ad = (const float*)d_in[7];
  const float* g1b  = (const float*)d_in[8];
  const float* g2W  = (const float*)d_in[9];
  const float* g2as = (const float*)d_in[10];
  const float* g2ad = (const float*)d_in[11];
  const float* g2b  = (const float*)d_in[12];
  const float* noW1 = (const float*)d_in[13];
  const float* nob1 = (const float*)d_in[14];
  const float* noW2 = (const float*)d_in[15];
  const float* nob2 = (const float*)d_in[16];
  const float* eoW1 = (const float*)d_in[17];
  const float* eob1 = (const float*)d_in[18];
  const float* eoW2 = (const float*)d_in[19];
  const float* eob2 = (const float*)d_in[20];

  const int N = in_sizes[0] / 2;
  const int E = in_sizes[1] / 2;
  const int* src = eidx;
  const int* dst = eidx + E;

  const int NB = (N + 127) >> 7;         // buckets of 128 nodes (<= 800)
  int avg = (E + NB - 1) / NB;
  int cap = avg + avg / 4 + 64;          // ~25% headroom
  if (cap > 2700) cap = 2700;            // LDS limit in k_bucket_build

  // workspace layout
  char* ws = (char*)d_ws;
  size_t off = 0;
  auto alloc = [&](size_t bytes) -> void* {
    void* p = ws + off;
    off = (off + bytes + 255) & ~(size_t)255;
    return p;
  };
  __half* bufA  = (__half*)alloc((size_t)N * 64 * 2);   // h1 -> h2 (fp16)
  __half* bufH  = (__half*)alloc((size_t)N * 64 * 2);   // hw1 -> hw2
  __half* P1h   = (__half*)alloc((size_t)N * 64 * 2);
  __half* P2h   = (__half*)alloc((size_t)N * 64 * 2);
  float*  as    = (float*) alloc((size_t)N * 4 * 4);
  float*  ad    = (float*) alloc((size_t)N * 4 * 4);
  int* rstart   = (int*)   alloc((size_t)N * 4);
  int* rend     = (int*)   alloc((size_t)N * 4);
  unsigned int* ebuf = (unsigned int*)alloc((size_t)NB * cap * 4);   // packed entries
  _Float16* palphaB = (_Float16*)alloc((size_t)NB * cap * 8);        // layer1 h4
  int* cursor   = (int*)   alloc((size_t)NB * 4);

  // ---- CSR build phase 1 + layer-1 hw/alphas (merged) ----
  hipMemsetAsync(cursor, 0, (size_t)NB * 4, stream);
  k_scatter_fuse<<<(E + 2047) / 2048, 256, 0, stream>>>(
      src, dst, E, NB, cap, cursor, ebuf,
      x, encW, encb, g1W, g1as, g1ad, bufH, as, ad, N);
  // ---- CSR build phase 2 + layer-1 edge numerators ----
  k_bucket_build<<<NB, 256, 0, stream>>>(cursor, cap, N, ebuf, rstart, rend,
                                         as, ad, (half4_t*)palphaB);
  // ---- layer-1 aggregation + ELU ----
  k_agg<4, true, false><<<(N + 3) / 4, 256, 0, stream>>>(bufH, palphaB, as, ad,
                                                         rstart, rend, ebuf, g1b, bufA, N);
  // ---- GAT layer 2 (palpha inlined in agg) ----
  k_hw_mfma<<<(N + 63) / 64, 256, 0, stream>>>(bufA, g2W, g2as, g2ad, bufH, as, ad, N);
  k_agg<1, false, true><<<(N + 3) / 4, 256, 0, stream>>>(bufH, palphaB, as, ad,
                                                         rstart, rend, ebuf, g2b, bufA, N);
  // ---- heads (fused P1/P2 + node head) ----
  float* out = (float*)d_out;
  k_heads_mfma<<<(N + 63) / 64, 256, 0, stream>>>(bufA, eoW1, noW1, nob1, noW2, nob2,
                                                  P1h, P2h, out + E, N);
  k_edge_head<<<2048, 256, 0, stream>>>(P1h, P2h, src, dst, ea,
                                        eoW1, eob1, eoW2, eob2, out, E);
}

// Round 15
// 361.936 us; speedup vs baseline: 1.0704x; 1.0451x over previous
//
#include <hip/hip_runtime.h>
#include <hip/hip_fp16.h>
#include <math.h>

// ---------------------------------------------------------------------------
// GAT model forward. N=100k nodes, E=1.6M edges, HID=64.
// R14 changes vs R13 (378.2us, best):
//  - layer-1 palpha eliminated: k_agg<4> computes the numerator in-loop from
//    the L2-resident alpha tables (same transform that worked for agg<1> in
//    R13). k_bucket_build loses its 51MB of random as4/ad4 gathers + 12.8MB
//    palpha4 write and reverts to a lean sort.
//  - everything else identical to R13. Edge head at structural 8-XCD
//    replication floor (184MB/3.1TB/s, invariant across 6 rounds); R8 agg
//    gather structure = proven local optimum (R9/R10 regressed).
// ---------------------------------------------------------------------------

typedef _Float16 half8_t __attribute__((ext_vector_type(8)));
typedef float floatx4 __attribute__((ext_vector_type(4)));

// Phase 1: bucket edges by dst>>7 (rank trick: count-pass atomic return IS the
// rank). Then grid-stride fuse1 tail: hw1 = fp16(x@Mc+c), H=4 alphas.
__global__ void k_scatter_fuse(const int* __restrict__ src, const int* __restrict__ dst,
                               int E, int NB, int cap, int* cursor,
                               unsigned int* __restrict__ ebuf,
                               const float* __restrict__ x,
                               const float* __restrict__ encW, const float* __restrict__ encb,
                               const float* __restrict__ g1W,
                               const float* __restrict__ g1as, const float* __restrict__ g1ad,
                               __half* __restrict__ hw, float* __restrict__ alpha_s,
                               float* __restrict__ alpha_d, int n){
  __shared__ int hist[800];
  __shared__ int base[800];
  __shared__ float McS[192];
  int t = threadIdx.x;                  // blockDim = 256
  if (t < 64){                          // per-block Mc (g1W is L2-resident)
    float m0 = 0.f, m1 = 0.f, cc = 0.f;
    for (int k = 0; k < 64; ++k){
      float g = g1W[k * 64 + t];
      m0 = fmaf(encW[k], g, m0);
      m1 = fmaf(encW[64 + k], g, m1);
      cc = fmaf(encb[k], g, cc);
    }
    McS[t] = m0; McS[64 + t] = m1; McS[128 + t] = cc;
  }
  for (int i = t; i < NB; i += 256) hist[i] = 0;
  __syncthreads();
  int cbase = blockIdx.x * 2048;
  int sv[8], bk[8], dl[8], rk[8];
  #pragma unroll
  for (int i = 0; i < 8; ++i){
    int e = cbase + i * 256 + t;
    if (e < E){
      int d = dst[e];
      sv[i] = src[e]; bk[i] = d >> 7; dl[i] = d & 127;
      rk[i] = atomicAdd(&hist[bk[i]], 1);   // rank within (block,bucket)
    } else bk[i] = -1;
  }
  __syncthreads();
  for (int i = t; i < NB; i += 256){
    int c = hist[i];
    base[i] = (c > 0) ? (i * cap + atomicAdd(&cursor[i], c)) : 0;
  }
  __syncthreads();
  #pragma unroll
  for (int i = 0; i < 8; ++i){
    if (bk[i] >= 0){
      int p = base[bk[i]] + rk[i];
      if (p < (bk[i] + 1) * cap)        // overflow guard (never fires in practice)
        ebuf[p] = (unsigned)sv[i] | ((unsigned)dl[i] << 17);
    }
  }
  // ---- fuse1 tail: grid-stride over n*64 channels ----
  int total = n * 64;
  int lane = t & 63;
  for (int idx = blockIdx.x * 256 + t; idx < total; idx += gridDim.x * 256){
    int node = idx >> 6;                // j == lane (idx base multiple of 64)
    float acc = fmaf(x[node * 2 + 0], McS[lane],
                fmaf(x[node * 2 + 1], McS[64 + lane], McS[128 + lane]));
    hw[idx] = __float2half(acc);
    float ps = acc * g1as[lane];
    float pd = acc * g1ad[lane];
    #pragma unroll
    for (int off = 1; off < 16; off <<= 1){
      ps += __shfl_xor(ps, off);
      pd += __shfl_xor(pd, off);
    }
    if ((lane & 15) == 0){
      int h = lane >> 4;
      alpha_s[node * 4 + h] = ps;
      alpha_d[node * 4 + h] = pd;
    }
  }
}

// Phase 2: one block (256 thr) per 128-node bucket. Sort in LDS ->
// rstart/rend + dst-sorted packed ebuf. (Lean: palpha moved into k_agg.)
__global__ void k_bucket_build(const int* __restrict__ cursor, int cap, int N,
                               unsigned int* ebuf, int* __restrict__ rstart,
                               int* __restrict__ rend){
  __shared__ unsigned int ent[2700];
  __shared__ unsigned short rank[2700];
  __shared__ int cnts[128];
  __shared__ int aux[128];
  int b = blockIdx.x, t = threadIdx.x;  // blockDim = 256
  int base = b * cap;
  int cnt = cursor[b];
  if (cnt > cap) cnt = cap;
  for (int i = t; i < cnt; i += 256) ent[i] = ebuf[base + i];
  if (t < 128) cnts[t] = 0;
  __syncthreads();
  for (int i = t; i < cnt; i += 256)
    rank[i] = (unsigned short)atomicAdd(&cnts[ent[i] >> 17], 1);
  __syncthreads();
  int v = 0;
  if (t < 128){ v = cnts[t]; aux[t] = v; }
  __syncthreads();
  for (int off = 1; off < 128; off <<= 1){
    int x = 0;
    if (t < 128 && t >= off) x = aux[t - off];
    __syncthreads();
    if (t < 128) aux[t] += x;
    __syncthreads();
  }
  if (t < 128){
    int incl = aux[t];
    int node = (b << 7) + t;
    if (node < N){ rstart[node] = base + incl - v; rend[node] = base + incl; }
    cnts[t] = incl - v;                 // per-node segment start (no atomics)
  }
  __syncthreads();
  for (int i = t; i < cnt; i += 256){
    unsigned int en = ent[i];
    int pos = cnts[en >> 17] + (int)rank[i];
    ebuf[base + pos] = en;              // keep packed (src|dl<<17)
  }
}

// MFMA GEMM: hw2 = fp16(h1 @ g2W); alpha_s/d (H=1) = rowsum(hw2 * a_{s,d}).
__global__ __launch_bounds__(256) void k_hw_mfma(
    const __half* __restrict__ hin, const float* __restrict__ W,
    const float* __restrict__ a_s, const float* __restrict__ a_d,
    __half* __restrict__ hw, float* __restrict__ alpha_s,
    float* __restrict__ alpha_d, int n){
  __shared__ float redS[4][16];
  __shared__ float redD[4][16];
  int t = threadIdx.x;
  int lane = t & 63, wave = t >> 6;
  int l15 = lane & 15, quad = lane >> 4;
  int ch = wave * 16 + l15;
  half8_t b0, b1;
  #pragma unroll
  for (int j = 0; j < 8; ++j){
    b0[j] = (_Float16)W[(quad * 8 + j) * 64 + ch];
    b1[j] = (_Float16)W[(quad * 8 + j + 32) * 64 + ch];
  }
  float asv = a_s[ch], adv = a_d[ch];
  int base = blockIdx.x * 64;
  for (int it = 0; it < 4; ++it){
    int tb = base + it * 16;
    if (tb >= n) break;
    int arn = tb + l15; if (arn >= n) arn = n - 1;
    const __half* arow = hin + (size_t)arn * 64 + quad * 8;
    half8_t a0 = *(const half8_t*)arow;
    half8_t a1 = *(const half8_t*)(arow + 32);
    floatx4 acc = {0.f, 0.f, 0.f, 0.f};
    acc = __builtin_amdgcn_mfma_f32_16x16x32_f16(a0, b0, acc, 0, 0, 0);
    acc = __builtin_amdgcn_mfma_f32_16x16x32_f16(a1, b1, acc, 0, 0, 0);
    float ps[4], pd[4];
    #pragma unroll
    for (int r = 0; r < 4; ++r){
      int node = tb + quad * 4 + r;
      if (node < n) hw[(size_t)node * 64 + ch] = __float2half(acc[r]);
      ps[r] = acc[r] * asv;
      pd[r] = acc[r] * adv;
      #pragma unroll
      for (int off = 1; off < 16; off <<= 1){
        ps[r] += __shfl_xor(ps[r], off);
        pd[r] += __shfl_xor(pd[r], off);
      }
    }
    if (l15 == 0){
      #pragma unroll
      for (int r = 0; r < 4; ++r){
        redS[wave][quad * 4 + r] = ps[r];
        redD[wave][quad * 4 + r] = pd[r];
      }
    }
    __syncthreads();
    if (t < 16 && tb + t < n){
      alpha_s[tb + t] = redS[0][t] + redS[1][t] + redS[2][t] + redS[3][t];
      alpha_d[tb + t] = redD[0][t] + redD[1][t] + redD[2][t] + redD[3][t];
    }
    __syncthreads();
  }
}

// Wave = 1 destination node, 8 edge-groups x 8 lanes; lane jj owns channels
// 8jj..8jj+7 (one 16B fp16 load per edge). Numerator computed in-loop from
// the L2-resident alpha tables: a = as[s*H+h] + ad[node*H+h] (ad loaded once
// per wave). [R8 gather structure: best measured across R9/R10 variants.]
template<int H, bool ELU_ACT>
__global__ void k_agg(const __half* __restrict__ hw,
                      const float* __restrict__ alpha_s, const float* __restrict__ alpha_d,
                      const int* __restrict__ rstart, const int* __restrict__ rend,
                      const unsigned int* __restrict__ ebuf,
                      const float* __restrict__ bias, __half* __restrict__ hout, int n){
  int node = (blockIdx.x * blockDim.x + threadIdx.x) >> 6;
  int lane = threadIdx.x & 63;
  int g = lane >> 3, jj = lane & 7;
  if (node >= n) return;
  int hidx = (jj * H) >> 3;                // head of channels 8jj..8jj+7
  int start = rstart[node], end = rend[node];
  float adn = alpha_d[node * H + hidx];
  float acc[8] = {0.f,0.f,0.f,0.f,0.f,0.f,0.f,0.f};
  float psum = 0.f;
  if (g == 0){                             // self loop (group 0 only)
    float a = alpha_s[node * H + hidx] + adn;
    a = a > 0.f ? a : 0.2f * a;
    float p = __expf(a);
    psum = p;
    float4 rv = *(const float4*)(hw + (size_t)node * 64 + jj * 8);
    const __half2* hp = (const __half2*)&rv;
    #pragma unroll
    for (int k = 0; k < 4; ++k){
      float2 f = __half22float2(hp[k]);
      acc[2 * k] = p * f.x; acc[2 * k + 1] = p * f.y;
    }
  }
  int i = start + g;
  for (; i + 8 < end; i += 16){
    unsigned int e0 = ebuf[i], e1 = ebuf[i + 8];
    int s0 = e0 & 0x1FFFF, s1 = e1 & 0x1FFFF;
    float a0 = alpha_s[s0 * H + hidx] + adn;
    float a1 = alpha_s[s1 * H + hidx] + adn;
    a0 = a0 > 0.f ? a0 : 0.2f * a0;
    a1 = a1 > 0.f ? a1 : 0.2f * a1;
    float p0 = __expf(a0), p1 = __expf(a1);
    float4 r0 = *(const float4*)(hw + (size_t)s0 * 64 + jj * 8);
    float4 r1 = *(const float4*)(hw + (size_t)s1 * 64 + jj * 8);
    const __half2* h0 = (const __half2*)&r0;
    const __half2* h1 = (const __half2*)&r1;
    psum += p0 + p1;
    #pragma unroll
    for (int k = 0; k < 4; ++k){
      float2 f0 = __half22float2(h0[k]);
      float2 f1 = __half22float2(h1[k]);
      acc[2 * k]     = fmaf(p0, f0.x, fmaf(p1, f1.x, acc[2 * k]));
      acc[2 * k + 1] = fmaf(p0, f0.y, fmaf(p1, f1.y, acc[2 * k + 1]));
    }
  }
  if (i < end){
    unsigned int en = ebuf[i];
    int s = en & 0x1FFFF;
    float a = alpha_s[s * H + hidx] + adn;
    a = a > 0.f ? a : 0.2f * a;
    float p = __expf(a);
    float4 rv = *(const float4*)(hw + (size_t)s * 64 + jj * 8);
    const __half2* hp = (const __half2*)&rv;
    psum += p;
    #pragma unroll
    for (int k = 0; k < 4; ++k){
      float2 f = __half22float2(hp[k]);
      acc[2 * k]     = fmaf(p, f.x, acc[2 * k]);
      acc[2 * k + 1] = fmaf(p, f.y, acc[2 * k + 1]);
    }
  }
  #pragma unroll
  for (int off = 8; off < 64; off <<= 1){
    psum += __shfl_xor(psum, off);
    #pragma unroll
    for (int k = 0; k < 8; ++k) acc[k] += __shfl_xor(acc[k], off);
  }
  if (g == 0){
    float inv = 1.f / (psum + 1e-16f);
    float4 bv0 = ((const float4*)bias)[2 * jj];
    float4 bv1 = ((const float4*)bias)[2 * jj + 1];
    float o[8];
    o[0] = fmaf(acc[0], inv, bv0.x); o[1] = fmaf(acc[1], inv, bv0.y);
    o[2] = fmaf(acc[2], inv, bv0.z); o[3] = fmaf(acc[3], inv, bv0.w);
    o[4] = fmaf(acc[4], inv, bv1.x); o[5] = fmaf(acc[5], inv, bv1.y);
    o[6] = fmaf(acc[6], inv, bv1.z); o[7] = fmaf(acc[7], inv, bv1.w);
    if (ELU_ACT){
      #pragma unroll
      for (int k = 0; k < 8; ++k) o[k] = o[k] > 0.f ? o[k] : (__expf(o[k]) - 1.f);
    }
    half8_t hv;
    #pragma unroll
    for (int k = 0; k < 8; ++k) hv[k] = (_Float16)o[k];
    *(half8_t*)(hout + (size_t)node * 64 + jj * 8) = hv;
  }
}

// Fused heads GEMMs over h2 (fp16): P1/P2 fp16 + node head, 6 MFMAs/wave-tile.
__global__ __launch_bounds__(256) void k_heads_mfma(
    const __half* __restrict__ h, const float* __restrict__ eoW1,
    const float* __restrict__ noW1, const float* __restrict__ nob1,
    const float* __restrict__ noW2, const float* __restrict__ nob2,
    __half* __restrict__ P1, __half* __restrict__ P2,
    float* __restrict__ outN, int n){
  __shared__ float redP[4][16][2];
  int t = threadIdx.x;
  int lane = t & 63, wave = t >> 6;
  int l15 = lane & 15, quad = lane >> 4;
  int ch = wave * 16 + l15;
  half8_t bP1a, bP1b, bP2a, bP2b, bNa, bNb;
  #pragma unroll
  for (int j = 0; j < 8; ++j){
    int k0 = quad * 8 + j, k1 = k0 + 32;
    bP1a[j] = (_Float16)eoW1[k0 * 64 + ch];
    bP1b[j] = (_Float16)eoW1[k1 * 64 + ch];
    bP2a[j] = (_Float16)eoW1[(k0 + 64) * 64 + ch];
    bP2b[j] = (_Float16)eoW1[(k1 + 64) * 64 + ch];
    bNa[j]  = (_Float16)noW1[k0 * 64 + ch];
    bNb[j]  = (_Float16)noW1[k1 * 64 + ch];
  }
  float b1v = nob1[ch];
  float w20 = noW2[ch * 2 + 0], w21 = noW2[ch * 2 + 1];
  float b20 = nob2[0], b21 = nob2[1];
  int base = blockIdx.x * 64;
  for (int it = 0; it < 4; ++it){
    int tb = base + it * 16;
    if (tb >= n) break;
    int arn = tb + l15; if (arn >= n) arn = n - 1;
    const __half* arow = h + (size_t)arn * 64 + quad * 8;
    half8_t a0 = *(const half8_t*)arow;
    half8_t a1 = *(const half8_t*)(arow + 32);
    floatx4 ac1 = {0.f,0.f,0.f,0.f}, ac2 = {0.f,0.f,0.f,0.f}, acN = {0.f,0.f,0.f,0.f};
    ac1 = __builtin_amdgcn_mfma_f32_16x16x32_f16(a0, bP1a, ac1, 0, 0, 0);
    ac1 = __builtin_amdgcn_mfma_f32_16x16x32_f16(a1, bP1b, ac1, 0, 0, 0);
    ac2 = __builtin_amdgcn_mfma_f32_16x16x32_f16(a0, bP2a, ac2, 0, 0, 0);
    ac2 = __builtin_amdgcn_mfma_f32_16x16x32_f16(a1, bP2b, ac2, 0, 0, 0);
    acN = __builtin_amdgcn_mfma_f32_16x16x32_f16(a0, bNa, acN, 0, 0, 0);
    acN = __builtin_amdgcn_mfma_f32_16x16x32_f16(a1, bNb, acN, 0, 0, 0);
    float p0[4], p1[4];
    #pragma unroll
    for (int r = 0; r < 4; ++r){
      int node = tb + quad * 4 + r;
      if (node < n){
        P1[(size_t)node * 64 + ch] = __float2half(ac1[r]);
        P2[(size_t)node * 64 + ch] = __float2half(ac2[r]);
      }
      float v = acN[r] + b1v;
      v = v > 0.f ? v : 0.01f * v;
      p0[r] = v * w20;
      p1[r] = v * w21;
      #pragma unroll
      for (int off = 1; off < 16; off <<= 1){
        p0[r] += __shfl_xor(p0[r], off);
        p1[r] += __shfl_xor(p1[r], off);
      }
    }
    if (l15 == 0){
      #pragma unroll
      for (int r = 0; r < 4; ++r){
        redP[wave][quad * 4 + r][0] = p0[r];
        redP[wave][quad * 4 + r][1] = p1[r];
      }
    }
    __syncthreads();
    if (t < 16 && tb + t < n){
      float s0 = redP[0][t][0] + redP[1][t][0] + redP[2][t][0] + redP[3][t][0];
      float s1 = redP[0][t][1] + redP[1][t][1] + redP[2][t][1] + redP[3][t][1];
      outN[(size_t)(tb + t) * 2 + 0] = tanhf(s0 + b20);
      outN[(size_t)(tb + t) * 2 + 1] = tanhf(s1 + b21);
    }
    __syncthreads();
  }
}

// 16 edges per wave-iteration: 8 groups of 8 lanes, each group handles edges
// e and e+8 (2x unroll -> 32 gathers in flight per wave).
__global__ void k_edge_head(const __half* __restrict__ P1h, const __half* __restrict__ P2h,
                            const int* __restrict__ src, const int* __restrict__ dst,
                            const float* __restrict__ eattr, const float* __restrict__ eoW1,
                            const float* __restrict__ b1, const float* __restrict__ W2,
                            const float* __restrict__ b2, float* __restrict__ out, int E){
  int lane = threadIdx.x & 63;
  int jj = lane & 7, q = lane >> 3;
  int wid = (blockIdx.x * blockDim.x + threadIdx.x) >> 6;
  int nw = (gridDim.x * blockDim.x) >> 6;

  const float4* rAq = (const float4*)(eoW1 + 8192);
  const float4* rBq = (const float4*)(eoW1 + 8256);
  const float4* b1q = (const float4*)b1;
  const float4* w2q = (const float4*)W2;
  float4 tA0 = rAq[2 * jj], tA1 = rAq[2 * jj + 1];
  float4 tB0 = rBq[2 * jj], tB1 = rBq[2 * jj + 1];
  float4 tb0 = b1q[2 * jj], tb1 = b1q[2 * jj + 1];
  float4 tw0 = w2q[2 * jj], tw1 = w2q[2 * jj + 1];
  float ra[8] = {tA0.x, tA0.y, tA0.z, tA0.w, tA1.x, tA1.y, tA1.z, tA1.w};
  float rb[8] = {tB0.x, tB0.y, tB0.z, tB0.w, tB1.x, tB1.y, tB1.z, tB1.w};
  float bb[8] = {tb0.x, tb0.y, tb0.z, tb0.w, tb1.x, tb1.y, tb1.z, tb1.w};
  float w2[8] = {tw0.x, tw0.y, tw0.z, tw0.w, tw1.x, tw1.y, tw1.z, tw1.w};
  float b2v = b2[0];

  const float4* P1q = (const float4*)P1h;
  const float4* P2q = (const float4*)P2h;
  const float2* eav = (const float2*)eattr;

  int groups = (E + 15) >> 4;
  for (int g = wid; g < groups; g += nw){
    int e0 = g * 16 + q, e1 = e0 + 8;
    bool act0 = (e0 < E), act1 = (e1 < E);
    float p0 = 0.f, p1 = 0.f;
    if (act0){
      int s = src[e0], d = dst[e0];
      float2 ea = eav[e0];
      float4 g1 = P1q[(size_t)s * 8 + jj];
      float4 g2 = P2q[(size_t)d * 8 + jj];
      const __half2* h1 = (const __half2*)&g1;
      const __half2* h2 = (const __half2*)&g2;
      #pragma unroll
      for (int k = 0; k < 4; ++k){
        float2 u = __half22float2(h1[k]);
        float2 w = __half22float2(h2[k]);
        float ta = u.x + w.x + bb[2 * k];
        float tb = u.y + w.y + bb[2 * k + 1];
        ta = fmaf(ea.x, ra[2 * k], fmaf(ea.y, rb[2 * k], ta));
        tb = fmaf(ea.x, ra[2 * k + 1], fmaf(ea.y, rb[2 * k + 1], tb));
        ta = ta > 0.f ? ta : 0.01f * ta;
        tb = tb > 0.f ? tb : 0.01f * tb;
        p0 = fmaf(ta, w2[2 * k], fmaf(tb, w2[2 * k + 1], p0));
      }
    }
    if (act1){
      int s = src[e1], d = dst[e1];
      float2 ea = eav[e1];
      float4 g1 = P1q[(size_t)s * 8 + jj];
      float4 g2 = P2q[(size_t)d * 8 + jj];
      const __half2* h1 = (const __half2*)&g1;
      const __half2* h2 = (const __half2*)&g2;
      #pragma unroll
      for (int k = 0; k < 4; ++k){
        float2 u = __half22float2(h1[k]);
        float2 w = __half22float2(h2[k]);
        float ta = u.x + w.x + bb[2 * k];
        float tb = u.y + w.y + bb[2 * k + 1];
        ta = fmaf(ea.x, ra[2 * k], fmaf(ea.y, rb[2 * k], ta));
        tb = fmaf(ea.x, ra[2 * k + 1], fmaf(ea.y, rb[2 * k + 1], tb));
        ta = ta > 0.f ? ta : 0.01f * ta;
        tb = tb > 0.f ? tb : 0.01f * tb;
        p1 = fmaf(ta, w2[2 * k], fmaf(tb, w2[2 * k + 1], p1));
      }
    }
    #pragma unroll
    for (int off = 1; off < 8; off <<= 1){
      p0 += __shfl_xor(p0, off);
      p1 += __shfl_xor(p1, off);
    }
    if (jj == 0){
      if (act0) out[e0] = tanhf(p0 + b2v);
      if (act1) out[e1] = tanhf(p1 + b2v);
    }
  }
}

extern "C" void kernel_launch(void* const* d_in, const int* in_sizes, int n_in,
                              void* d_out, int out_size, void* d_ws, size_t ws_size,
                              hipStream_t stream){
  const float* x    = (const float*)d_in[0];
  const int*   eidx = (const int*)  d_in[1];
  const float* ea   = (const float*)d_in[2];
  const float* encW = (const float*)d_in[3];
  const float* encb = (const float*)d_in[4];
  const float* g1W  = (const float*)d_in[5];
  const float* g1as = (const float*)d_in[6];
  const float* g1ad = (const float*)d_in[7];
  const float* g1b  = (const float*)d_in[8];
  const float* g2W  = (const float*)d_in[9];
  const float* g2as = (const float*)d_in[10];
  const float* g2ad = (const float*)d_in[11];
  const float* g2b  = (const float*)d_in[12];
  const float* noW1 = (const float*)d_in[13];
  const float* nob1 = (const float*)d_in[14];
  const float* noW2 = (const float*)d_in[15];
  const float* nob2 = (const float*)d_in[16];
  const float* eoW1 = (const float*)d_in[17];
  const float* eob1 = (const float*)d_in[18];
  const float* eoW2 = (const float*)d_in[19];
  const float* eob2 = (const float*)d_in[20];

  const int N = in_sizes[0] / 2;
  const int E = in_sizes[1] / 2;
  const int* src = eidx;
  const int* dst = eidx + E;

  const int NB = (N + 127) >> 7;         // buckets of 128 nodes (<= 800)
  int avg = (E + NB - 1) / NB;
  int cap = avg + avg / 4 + 64;          // ~25% headroom
  if (cap > 2700) cap = 2700;            // LDS limit in k_bucket_build

  // workspace layout
  char* ws = (char*)d_ws;
  size_t off = 0;
  auto alloc = [&](size_t bytes) -> void* {
    void* p = ws + off;
    off = (off + bytes + 255) & ~(size_t)255;
    return p;
  };
  __half* bufA  = (__half*)alloc((size_t)N * 64 * 2);   // h1 -> h2 (fp16)
  __half* bufH  = (__half*)alloc((size_t)N * 64 * 2);   // hw1 -> hw2
  __half* P1h   = (__half*)alloc((size_t)N * 64 * 2);
  __half* P2h   = (__half*)alloc((size_t)N * 64 * 2);
  float*  as    = (float*) alloc((size_t)N * 4 * 4);
  float*  ad    = (float*) alloc((size_t)N * 4 * 4);
  int* rstart   = (int*)   alloc((size_t)N * 4);
  int* rend     = (int*)   alloc((size_t)N * 4);
  unsigned int* ebuf = (unsigned int*)alloc((size_t)NB * cap * 4);   // packed entries
  int* cursor   = (int*)   alloc((size_t)NB * 4);

  // ---- CSR build phase 1 + layer-1 hw/alphas (merged) ----
  hipMemsetAsync(cursor, 0, (size_t)NB * 4, stream);
  k_scatter_fuse<<<(E + 2047) / 2048, 256, 0, stream>>>(
      src, dst, E, NB, cap, cursor, ebuf,
      x, encW, encb, g1W, g1as, g1ad, bufH, as, ad, N);
  // ---- CSR build phase 2 (lean sort) ----
  k_bucket_build<<<NB, 256, 0, stream>>>(cursor, cap, N, ebuf, rstart, rend);
  // ---- layer-1 aggregation + ELU (numerator inline) ----
  k_agg<4, true><<<(N + 3) / 4, 256, 0, stream>>>(bufH, as, ad,
                                                  rstart, rend, ebuf, g1b, bufA, N);
  // ---- GAT layer 2 (numerator inline) ----
  k_hw_mfma<<<(N + 63) / 64, 256, 0, stream>>>(bufA, g2W, g2as, g2ad, bufH, as, ad, N);
  k_agg<1, false><<<(N + 3) / 4, 256, 0, stream>>>(bufH, as, ad,
                                                   rstart, rend, ebuf, g2b, bufA, N);
  // ---- heads (fused P1/P2 + node head) ----
  float* out = (float*)d_out;
  k_heads_mfma<<<(N + 63) / 64, 256, 0, stream>>>(bufA, eoW1, noW1, nob1, noW2, nob2,
                                                  P1h, P2h, out + E, N);
  k_edge_head<<<2048, 256, 0, stream>>>(P1h, P2h, src, dst, ea,
                                        eoW1, eob1, eoW2, eob2, out, E);
}

// Round 16
// 358.819 us; speedup vs baseline: 1.0797x; 1.0087x over previous
//
#include <hip/hip_runtime.h>
#include <hip/hip_fp16.h>
#include <math.h>

// ---------------------------------------------------------------------------
// GAT model forward. N=100k nodes, E=1.6M edges, HID=64.
// R15 changes vs R14 (362.0us, best):
//  - k_hw_mfma: alpha rowsum factored as h1·(W@a) -> 2 extra MFMAs on wave 0
//    (B = [v_s|v_d|0..], v precomputed in scatter block 0). Kernel now has
//    zero barriers / zero LDS / zero shfls.
//  - rstart/rend packed into one int2 array (single 8B load per agg wave).
//  - everything else identical to R14. Edge head at structural 8-XCD
//    replication floor (184MB/3.1TB/s, invariant across 7 rounds).
// ---------------------------------------------------------------------------

typedef _Float16 half8_t __attribute__((ext_vector_type(8)));
typedef float floatx4 __attribute__((ext_vector_type(4)));

// Phase 1: bucket edges by dst>>7 (rank trick). Block 0 also computes
// vsd = [g2W@g2as ; g2W@g2ad] for k_hw_mfma's factored alpha MFMA.
// Then grid-stride fuse1 tail: hw1 = fp16(x@Mc+c), H=4 alphas.
__global__ void k_scatter_fuse(const int* __restrict__ src, const int* __restrict__ dst,
                               int E, int NB, int cap, int* cursor,
                               unsigned int* __restrict__ ebuf,
                               const float* __restrict__ x,
                               const float* __restrict__ encW, const float* __restrict__ encb,
                               const float* __restrict__ g1W,
                               const float* __restrict__ g1as, const float* __restrict__ g1ad,
                               const float* __restrict__ g2W,
                               const float* __restrict__ g2as, const float* __restrict__ g2ad,
                               float* __restrict__ vsd,
                               __half* __restrict__ hw, float* __restrict__ alpha_s,
                               float* __restrict__ alpha_d, int n){
  __shared__ int hist[800];
  __shared__ int base[800];
  __shared__ float McS[192];
  int t = threadIdx.x;                  // blockDim = 256
  if (t < 64){                          // per-block Mc (g1W is L2-resident)
    float m0 = 0.f, m1 = 0.f, cc = 0.f;
    for (int k = 0; k < 64; ++k){
      float g = g1W[k * 64 + t];
      m0 = fmaf(encW[k], g, m0);
      m1 = fmaf(encW[64 + k], g, m1);
      cc = fmaf(encb[k], g, cc);
    }
    McS[t] = m0; McS[64 + t] = m1; McS[128 + t] = cc;
  }
  if (blockIdx.x == 0 && t < 64){       // vsd[k] = sum_ch g2W[k][ch]*a_{s,d}[ch]
    float vs = 0.f, vd = 0.f;
    for (int ch = 0; ch < 64; ++ch){
      float g = g2W[t * 64 + ch];
      vs = fmaf(g, g2as[ch], vs);
      vd = fmaf(g, g2ad[ch], vd);
    }
    vsd[t] = vs; vsd[64 + t] = vd;
  }
  for (int i = t; i < NB; i += 256) hist[i] = 0;
  __syncthreads();
  int cbase = blockIdx.x * 2048;
  int sv[8], bk[8], dl[8], rk[8];
  #pragma unroll
  for (int i = 0; i < 8; ++i){
    int e = cbase + i * 256 + t;
    if (e < E){
      int d = dst[e];
      sv[i] = src[e]; bk[i] = d >> 7; dl[i] = d & 127;
      rk[i] = atomicAdd(&hist[bk[i]], 1);   // rank within (block,bucket)
    } else bk[i] = -1;
  }
  __syncthreads();
  for (int i = t; i < NB; i += 256){
    int c = hist[i];
    base[i] = (c > 0) ? (i * cap + atomicAdd(&cursor[i], c)) : 0;
  }
  __syncthreads();
  #pragma unroll
  for (int i = 0; i < 8; ++i){
    if (bk[i] >= 0){
      int p = base[bk[i]] + rk[i];
      if (p < (bk[i] + 1) * cap)        // overflow guard (never fires in practice)
        ebuf[p] = (unsigned)sv[i] | ((unsigned)dl[i] << 17);
    }
  }
  // ---- fuse1 tail: grid-stride over n*64 channels ----
  int total = n * 64;
  int lane = t & 63;
  for (int idx = blockIdx.x * 256 + t; idx < total; idx += gridDim.x * 256){
    int node = idx >> 6;                // j == lane (idx base multiple of 64)
    float acc = fmaf(x[node * 2 + 0], McS[lane],
                fmaf(x[node * 2 + 1], McS[64 + lane], McS[128 + lane]));
    hw[idx] = __float2half(acc);
    float ps = acc * g1as[lane];
    float pd = acc * g1ad[lane];
    #pragma unroll
    for (int off = 1; off < 16; off <<= 1){
      ps += __shfl_xor(ps, off);
      pd += __shfl_xor(pd, off);
    }
    if ((lane & 15) == 0){
      int h = lane >> 4;
      alpha_s[node * 4 + h] = ps;
      alpha_d[node * 4 + h] = pd;
    }
  }
}

// Phase 2: one block (256 thr) per 128-node bucket. Sort in LDS ->
// rowrange (int2) + dst-sorted packed ebuf.
__global__ void k_bucket_build(const int* __restrict__ cursor, int cap, int N,
                               unsigned int* ebuf, int2* __restrict__ rowrange){
  __shared__ unsigned int ent[2700];
  __shared__ unsigned short rank[2700];
  __shared__ int cnts[128];
  __shared__ int aux[128];
  int b = blockIdx.x, t = threadIdx.x;  // blockDim = 256
  int base = b * cap;
  int cnt = cursor[b];
  if (cnt > cap) cnt = cap;
  for (int i = t; i < cnt; i += 256) ent[i] = ebuf[base + i];
  if (t < 128) cnts[t] = 0;
  __syncthreads();
  for (int i = t; i < cnt; i += 256)
    rank[i] = (unsigned short)atomicAdd(&cnts[ent[i] >> 17], 1);
  __syncthreads();
  int v = 0;
  if (t < 128){ v = cnts[t]; aux[t] = v; }
  __syncthreads();
  for (int off = 1; off < 128; off <<= 1){
    int x = 0;
    if (t < 128 && t >= off) x = aux[t - off];
    __syncthreads();
    if (t < 128) aux[t] += x;
    __syncthreads();
  }
  if (t < 128){
    int incl = aux[t];
    int node = (b << 7) + t;
    if (node < N) rowrange[node] = make_int2(base + incl - v, base + incl);
    cnts[t] = incl - v;                 // per-node segment start (no atomics)
  }
  __syncthreads();
  for (int i = t; i < cnt; i += 256){
    unsigned int en = ent[i];
    int pos = cnts[en >> 17] + (int)rank[i];
    ebuf[base + pos] = en;              // keep packed (src|dl<<17)
  }
}

// MFMA GEMM: hw2 = fp16(h1 @ g2W); alphas via factored MFMA on wave 0:
// alpha_{s,d}[node] = h1[node,:] . vsd  (B cols [v_s|v_d|0..]).
// Zero barriers, zero LDS.
__global__ __launch_bounds__(256) void k_hw_mfma(
    const __half* __restrict__ hin, const float* __restrict__ W,
    const float* __restrict__ vsd,
    __half* __restrict__ hw, float* __restrict__ alpha_s,
    float* __restrict__ alpha_d, int n){
  int t = threadIdx.x;
  int lane = t & 63, wave = t >> 6;
  int l15 = lane & 15, quad = lane >> 4;
  int ch = wave * 16 + l15;
  half8_t b0, b1;
  #pragma unroll
  for (int j = 0; j < 8; ++j){
    b0[j] = (_Float16)W[(quad * 8 + j) * 64 + ch];
    b1[j] = (_Float16)W[(quad * 8 + j + 32) * 64 + ch];
  }
  half8_t bA0 = {0,0,0,0,0,0,0,0}, bA1 = {0,0,0,0,0,0,0,0};
  if (wave == 0 && l15 < 2){
    const float* v = vsd + l15 * 64;
    #pragma unroll
    for (int j = 0; j < 8; ++j){
      bA0[j] = (_Float16)v[quad * 8 + j];
      bA1[j] = (_Float16)v[quad * 8 + j + 32];
    }
  }
  int base = blockIdx.x * 64;
  for (int it = 0; it < 4; ++it){
    int tb = base + it * 16;
    if (tb >= n) break;
    int arn = tb + l15; if (arn >= n) arn = n - 1;
    const __half* arow = hin + (size_t)arn * 64 + quad * 8;
    half8_t a0 = *(const half8_t*)arow;
    half8_t a1 = *(const half8_t*)(arow + 32);
    floatx4 acc = {0.f, 0.f, 0.f, 0.f};
    acc = __builtin_amdgcn_mfma_f32_16x16x32_f16(a0, b0, acc, 0, 0, 0);
    acc = __builtin_amdgcn_mfma_f32_16x16x32_f16(a1, b1, acc, 0, 0, 0);
    #pragma unroll
    for (int r = 0; r < 4; ++r){
      int node = tb + quad * 4 + r;
      if (node < n) hw[(size_t)node * 64 + ch] = __float2half(acc[r]);
    }
    if (wave == 0){
      floatx4 accA = {0.f, 0.f, 0.f, 0.f};
      accA = __builtin_amdgcn_mfma_f32_16x16x32_f16(a0, bA0, accA, 0, 0, 0);
      accA = __builtin_amdgcn_mfma_f32_16x16x32_f16(a1, bA1, accA, 0, 0, 0);
      if (l15 < 2){
        float* dstp = (l15 == 0) ? alpha_s : alpha_d;
        #pragma unroll
        for (int r = 0; r < 4; ++r){
          int node = tb + quad * 4 + r;
          if (node < n) dstp[node] = accA[r];
        }
      }
    }
  }
}

// Wave = 1 destination node, 8 edge-groups x 8 lanes; lane jj owns channels
// 8jj..8jj+7 (one 16B fp16 load per edge). Numerator computed in-loop from
// the L2-resident alpha tables. [R8 gather structure: best measured.]
template<int H, bool ELU_ACT>
__global__ void k_agg(const __half* __restrict__ hw,
                      const float* __restrict__ alpha_s, const float* __restrict__ alpha_d,
                      const int2* __restrict__ rowrange,
                      const unsigned int* __restrict__ ebuf,
                      const float* __restrict__ bias, __half* __restrict__ hout, int n){
  int node = (blockIdx.x * blockDim.x + threadIdx.x) >> 6;
  int lane = threadIdx.x & 63;
  int g = lane >> 3, jj = lane & 7;
  if (node >= n) return;
  int hidx = (jj * H) >> 3;                // head of channels 8jj..8jj+7
  int2 rr = rowrange[node];
  int start = rr.x, end = rr.y;
  float adn = alpha_d[node * H + hidx];
  float acc[8] = {0.f,0.f,0.f,0.f,0.f,0.f,0.f,0.f};
  float psum = 0.f;
  if (g == 0){                             // self loop (group 0 only)
    float a = alpha_s[node * H + hidx] + adn;
    a = a > 0.f ? a : 0.2f * a;
    float p = __expf(a);
    psum = p;
    float4 rv = *(const float4*)(hw + (size_t)node * 64 + jj * 8);
    const __half2* hp = (const __half2*)&rv;
    #pragma unroll
    for (int k = 0; k < 4; ++k){
      float2 f = __half22float2(hp[k]);
      acc[2 * k] = p * f.x; acc[2 * k + 1] = p * f.y;
    }
  }
  int i = start + g;
  for (; i + 8 < end; i += 16){
    unsigned int e0 = ebuf[i], e1 = ebuf[i + 8];
    int s0 = e0 & 0x1FFFF, s1 = e1 & 0x1FFFF;
    float a0 = alpha_s[s0 * H + hidx] + adn;
    float a1 = alpha_s[s1 * H + hidx] + adn;
    a0 = a0 > 0.f ? a0 : 0.2f * a0;
    a1 = a1 > 0.f ? a1 : 0.2f * a1;
    float p0 = __expf(a0), p1 = __expf(a1);
    float4 r0 = *(const float4*)(hw + (size_t)s0 * 64 + jj * 8);
    float4 r1 = *(const float4*)(hw + (size_t)s1 * 64 + jj * 8);
    const __half2* h0 = (const __half2*)&r0;
    const __half2* h1 = (const __half2*)&r1;
    psum += p0 + p1;
    #pragma unroll
    for (int k = 0; k < 4; ++k){
      float2 f0 = __half22float2(h0[k]);
      float2 f1 = __half22float2(h1[k]);
      acc[2 * k]     = fmaf(p0, f0.x, fmaf(p1, f1.x, acc[2 * k]));
      acc[2 * k + 1] = fmaf(p0, f0.y, fmaf(p1, f1.y, acc[2 * k + 1]));
    }
  }
  if (i < end){
    unsigned int en = ebuf[i];
    int s = en & 0x1FFFF;
    float a = alpha_s[s * H + hidx] + adn;
    a = a > 0.f ? a : 0.2f * a;
    float p = __expf(a);
    float4 rv = *(const float4*)(hw + (size_t)s * 64 + jj * 8);
    const __half2* hp = (const __half2*)&rv;
    psum += p;
    #pragma unroll
    for (int k = 0; k < 4; ++k){
      float2 f = __half22float2(hp[k]);
      acc[2 * k]     = fmaf(p, f.x, acc[2 * k]);
      acc[2 * k + 1] = fmaf(p, f.y, acc[2 * k + 1]);
    }
  }
  #pragma unroll
  for (int off = 8; off < 64; off <<= 1){
    psum += __shfl_xor(psum, off);
    #pragma unroll
    for (int k = 0; k < 8; ++k) acc[k] += __shfl_xor(acc[k], off);
  }
  if (g == 0){
    float inv = 1.f / (psum + 1e-16f);
    float4 bv0 = ((const float4*)bias)[2 * jj];
    float4 bv1 = ((const float4*)bias)[2 * jj + 1];
    float o[8];
    o[0] = fmaf(acc[0], inv, bv0.x); o[1] = fmaf(acc[1], inv, bv0.y);
    o[2] = fmaf(acc[2], inv, bv0.z); o[3] = fmaf(acc[3], inv, bv0.w);
    o[4] = fmaf(acc[4], inv, bv1.x); o[5] = fmaf(acc[5], inv, bv1.y);
    o[6] = fmaf(acc[6], inv, bv1.z); o[7] = fmaf(acc[7], inv, bv1.w);
    if (ELU_ACT){
      #pragma unroll
      for (int k = 0; k < 8; ++k) o[k] = o[k] > 0.f ? o[k] : (__expf(o[k]) - 1.f);
    }
    half8_t hv;
    #pragma unroll
    for (int k = 0; k < 8; ++k) hv[k] = (_Float16)o[k];
    *(half8_t*)(hout + (size_t)node * 64 + jj * 8) = hv;
  }
}

// Fused heads GEMMs over h2 (fp16): P1/P2 fp16 + node head, 6 MFMAs/wave-tile.
__global__ __launch_bounds__(256) void k_heads_mfma(
    const __half* __restrict__ h, const float* __restrict__ eoW1,
    const float* __restrict__ noW1, const float* __restrict__ nob1,
    const float* __restrict__ noW2, const float* __restrict__ nob2,
    __half* __restrict__ P1, __half* __restrict__ P2,
    float* __restrict__ outN, int n){
  __shared__ float redP[4][16][2];
  int t = threadIdx.x;
  int lane = t & 63, wave = t >> 6;
  int l15 = lane & 15, quad = lane >> 4;
  int ch = wave * 16 + l15;
  half8_t bP1a, bP1b, bP2a, bP2b, bNa, bNb;
  #pragma unroll
  for (int j = 0; j < 8; ++j){
    int k0 = quad * 8 + j, k1 = k0 + 32;
    bP1a[j] = (_Float16)eoW1[k0 * 64 + ch];
    bP1b[j] = (_Float16)eoW1[k1 * 64 + ch];
    bP2a[j] = (_Float16)eoW1[(k0 + 64) * 64 + ch];
    bP2b[j] = (_Float16)eoW1[(k1 + 64) * 64 + ch];
    bNa[j]  = (_Float16)noW1[k0 * 64 + ch];
    bNb[j]  = (_Float16)noW1[k1 * 64 + ch];
  }
  float b1v = nob1[ch];
  float w20 = noW2[ch * 2 + 0], w21 = noW2[ch * 2 + 1];
  float b20 = nob2[0], b21 = nob2[1];
  int base = blockIdx.x * 64;
  for (int it = 0; it < 4; ++it){
    int tb = base + it * 16;
    if (tb >= n) break;
    int arn = tb + l15; if (arn >= n) arn = n - 1;
    const __half* arow = h + (size_t)arn * 64 + quad * 8;
    half8_t a0 = *(const half8_t*)arow;
    half8_t a1 = *(const half8_t*)(arow + 32);
    floatx4 ac1 = {0.f,0.f,0.f,0.f}, ac2 = {0.f,0.f,0.f,0.f}, acN = {0.f,0.f,0.f,0.f};
    ac1 = __builtin_amdgcn_mfma_f32_16x16x32_f16(a0, bP1a, ac1, 0, 0, 0);
    ac1 = __builtin_amdgcn_mfma_f32_16x16x32_f16(a1, bP1b, ac1, 0, 0, 0);
    ac2 = __builtin_amdgcn_mfma_f32_16x16x32_f16(a0, bP2a, ac2, 0, 0, 0);
    ac2 = __builtin_amdgcn_mfma_f32_16x16x32_f16(a1, bP2b, ac2, 0, 0, 0);
    acN = __builtin_amdgcn_mfma_f32_16x16x32_f16(a0, bNa, acN, 0, 0, 0);
    acN = __builtin_amdgcn_mfma_f32_16x16x32_f16(a1, bNb, acN, 0, 0, 0);
    float p0[4], p1[4];
    #pragma unroll
    for (int r = 0; r < 4; ++r){
      int node = tb + quad * 4 + r;
      if (node < n){
        P1[(size_t)node * 64 + ch] = __float2half(ac1[r]);
        P2[(size_t)node * 64 + ch] = __float2half(ac2[r]);
      }
      float v = acN[r] + b1v;
      v = v > 0.f ? v : 0.01f * v;
      p0[r] = v * w20;
      p1[r] = v * w21;
      #pragma unroll
      for (int off = 1; off < 16; off <<= 1){
        p0[r] += __shfl_xor(p0[r], off);
        p1[r] += __shfl_xor(p1[r], off);
      }
    }
    if (l15 == 0){
      #pragma unroll
      for (int r = 0; r < 4; ++r){
        redP[wave][quad * 4 + r][0] = p0[r];
        redP[wave][quad * 4 + r][1] = p1[r];
      }
    }
    __syncthreads();
    if (t < 16 && tb + t < n){
      float s0 = redP[0][t][0] + redP[1][t][0] + redP[2][t][0] + redP[3][t][0];
      float s1 = redP[0][t][1] + redP[1][t][1] + redP[2][t][1] + redP[3][t][1];
      outN[(size_t)(tb + t) * 2 + 0] = tanhf(s0 + b20);
      outN[(size_t)(tb + t) * 2 + 1] = tanhf(s1 + b21);
    }
    __syncthreads();
  }
}

// 16 edges per wave-iteration: 8 groups of 8 lanes, each group handles edges
// e and e+8 (2x unroll -> 32 gathers in flight per wave).
__global__ void k_edge_head(const __half* __restrict__ P1h, const __half* __restrict__ P2h,
                            const int* __restrict__ src, const int* __restrict__ dst,
                            const float* __restrict__ eattr, const float* __restrict__ eoW1,
                            const float* __restrict__ b1, const float* __restrict__ W2,
                            const float* __restrict__ b2, float* __restrict__ out, int E){
  int lane = threadIdx.x & 63;
  int jj = lane & 7, q = lane >> 3;
  int wid = (blockIdx.x * blockDim.x + threadIdx.x) >> 6;
  int nw = (gridDim.x * blockDim.x) >> 6;

  const float4* rAq = (const float4*)(eoW1 + 8192);
  const float4* rBq = (const float4*)(eoW1 + 8256);
  const float4* b1q = (const float4*)b1;
  const float4* w2q = (const float4*)W2;
  float4 tA0 = rAq[2 * jj], tA1 = rAq[2 * jj + 1];
  float4 tB0 = rBq[2 * jj], tB1 = rBq[2 * jj + 1];
  float4 tb0 = b1q[2 * jj], tb1 = b1q[2 * jj + 1];
  float4 tw0 = w2q[2 * jj], tw1 = w2q[2 * jj + 1];
  float ra[8] = {tA0.x, tA0.y, tA0.z, tA0.w, tA1.x, tA1.y, tA1.z, tA1.w};
  float rb[8] = {tB0.x, tB0.y, tB0.z, tB0.w, tB1.x, tB1.y, tB1.z, tB1.w};
  float bb[8] = {tb0.x, tb0.y, tb0.z, tb0.w, tb1.x, tb1.y, tb1.z, tb1.w};
  float w2[8] = {tw0.x, tw0.y, tw0.z, tw0.w, tw1.x, tw1.y, tw1.z, tw1.w};
  float b2v = b2[0];

  const float4* P1q = (const float4*)P1h;
  const float4* P2q = (const float4*)P2h;
  const float2* eav = (const float2*)eattr;

  int groups = (E + 15) >> 4;
  for (int g = wid; g < groups; g += nw){
    int e0 = g * 16 + q, e1 = e0 + 8;
    bool act0 = (e0 < E), act1 = (e1 < E);
    float p0 = 0.f, p1 = 0.f;
    if (act0){
      int s = src[e0], d = dst[e0];
      float2 ea = eav[e0];
      float4 g1 = P1q[(size_t)s * 8 + jj];
      float4 g2 = P2q[(size_t)d * 8 + jj];
      const __half2* h1 = (const __half2*)&g1;
      const __half2* h2 = (const __half2*)&g2;
      #pragma unroll
      for (int k = 0; k < 4; ++k){
        float2 u = __half22float2(h1[k]);
        float2 w = __half22float2(h2[k]);
        float ta = u.x + w.x + bb[2 * k];
        float tb = u.y + w.y + bb[2 * k + 1];
        ta = fmaf(ea.x, ra[2 * k], fmaf(ea.y, rb[2 * k], ta));
        tb = fmaf(ea.x, ra[2 * k + 1], fmaf(ea.y, rb[2 * k + 1], tb));
        ta = ta > 0.f ? ta : 0.01f * ta;
        tb = tb > 0.f ? tb : 0.01f * tb;
        p0 = fmaf(ta, w2[2 * k], fmaf(tb, w2[2 * k + 1], p0));
      }
    }
    if (act1){
      int s = src[e1], d = dst[e1];
      float2 ea = eav[e1];
      float4 g1 = P1q[(size_t)s * 8 + jj];
      float4 g2 = P2q[(size_t)d * 8 + jj];
      const __half2* h1 = (const __half2*)&g1;
      const __half2* h2 = (const __half2*)&g2;
      #pragma unroll
      for (int k = 0; k < 4; ++k){
        float2 u = __half22float2(h1[k]);
        float2 w = __half22float2(h2[k]);
        float ta = u.x + w.x + bb[2 * k];
        float tb = u.y + w.y + bb[2 * k + 1];
        ta = fmaf(ea.x, ra[2 * k], fmaf(ea.y, rb[2 * k], ta));
        tb = fmaf(ea.x, ra[2 * k + 1], fmaf(ea.y, rb[2 * k + 1], tb));
        ta = ta > 0.f ? ta : 0.01f * ta;
        tb = tb > 0.f ? tb : 0.01f * tb;
        p1 = fmaf(ta, w2[2 * k], fmaf(tb, w2[2 * k + 1], p1));
      }
    }
    #pragma unroll
    for (int off = 1; off < 8; off <<= 1){
      p0 += __shfl_xor(p0, off);
      p1 += __shfl_xor(p1, off);
    }
    if (jj == 0){
      if (act0) out[e0] = tanhf(p0 + b2v);
      if (act1) out[e1] = tanhf(p1 + b2v);
    }
  }
}

extern "C" void kernel_launch(void* const* d_in, const int* in_sizes, int n_in,
                              void* d_out, int out_size, void* d_ws, size_t ws_size,
                              hipStream_t stream){
  const float* x    = (const float*)d_in[0];
  const int*   eidx = (const int*)  d_in[1];
  const float* ea   = (const float*)d_in[2];
  const float* encW = (const float*)d_in[3];
  const float* encb = (const float*)d_in[4];
  const float* g1W  = (const float*)d_in[5];
  const float* g1as = (const float*)d_in[6];
  const float* g1ad = (const float*)d_in[7];
  const float* g1b  = (const float*)d_in[8];
  const float* g2W  = (const float*)d_in[9];
  const float* g2as = (const float*)d_in[10];
  const float* g2ad = (const float*)d_in[11];
  const float* g2b  = (const float*)d_in[12];
  const float* noW1 = (const float*)d_in[13];
  const float* nob1 = (const float*)d_in[14];
  const float* noW2 = (const float*)d_in[15];
  const float* nob2 = (const float*)d_in[16];
  const float* eoW1 = (const float*)d_in[17];
  const float* eob1 = (const float*)d_in[18];
  const float* eoW2 = (const float*)d_in[19];
  const float* eob2 = (const float*)d_in[20];

  const int N = in_sizes[0] / 2;
  const int E = in_sizes[1] / 2;
  const int* src = eidx;
  const int* dst = eidx + E;

  const int NB = (N + 127) >> 7;         // buckets of 128 nodes (<= 800)
  int avg = (E + NB - 1) / NB;
  int cap = avg + avg / 4 + 64;          // ~25% headroom
  if (cap > 2700) cap = 2700;            // LDS limit in k_bucket_build

  // workspace layout
  char* ws = (char*)d_ws;
  size_t off = 0;
  auto alloc = [&](size_t bytes) -> void* {
    void* p = ws + off;
    off = (off + bytes + 255) & ~(size_t)255;
    return p;
  };
  __half* bufA  = (__half*)alloc((size_t)N * 64 * 2);   // h1 -> h2 (fp16)
  __half* bufH  = (__half*)alloc((size_t)N * 64 * 2);   // hw1 -> hw2
  __half* P1h   = (__half*)alloc((size_t)N * 64 * 2);
  __half* P2h   = (__half*)alloc((size_t)N * 64 * 2);
  float*  as    = (float*) alloc((size_t)N * 4 * 4);
  float*  ad    = (float*) alloc((size_t)N * 4 * 4);
  int2* rowrange = (int2*) alloc((size_t)N * 8);
  unsigned int* ebuf = (unsigned int*)alloc((size_t)NB * cap * 4);   // packed entries
  int* cursor   = (int*)   alloc((size_t)NB * 4);
  float* vsd    = (float*) alloc(128 * 4);              // [g2W@g2as ; g2W@g2ad]

  // ---- CSR build phase 1 + layer-1 hw/alphas + vsd precompute (merged) ----
  hipMemsetAsync(cursor, 0, (size_t)NB * 4, stream);
  k_scatter_fuse<<<(E + 2047) / 2048, 256, 0, stream>>>(
      src, dst, E, NB, cap, cursor, ebuf,
      x, encW, encb, g1W, g1as, g1ad, g2W, g2as, g2ad, vsd, bufH, as, ad, N);
  // ---- CSR build phase 2 (lean sort) ----
  k_bucket_build<<<NB, 256, 0, stream>>>(cursor, cap, N, ebuf, rowrange);
  // ---- layer-1 aggregation + ELU (numerator inline) ----
  k_agg<4, true><<<(N + 3) / 4, 256, 0, stream>>>(bufH, as, ad,
                                                  rowrange, ebuf, g1b, bufA, N);
  // ---- GAT layer 2 (alphas via factored MFMA; numerator inline in agg) ----
  k_hw_mfma<<<(N + 63) / 64, 256, 0, stream>>>(bufA, g2W, vsd, bufH, as, ad, N);
  k_agg<1, false><<<(N + 3) / 4, 256, 0, stream>>>(bufH, as, ad,
                                                   rowrange, ebuf, g2b, bufA, N);
  // ---- heads (fused P1/P2 + node head) ----
  float* out = (float*)d_out;
  k_heads_mfma<<<(N + 63) / 64, 256, 0, stream>>>(bufA, eoW1, noW1, nob1, noW2, nob2,
                                                  P1h, P2h, out + E, N);
  k_edge_head<<<2048, 256, 0, stream>>>(P1h, P2h, src, dst, ea,
                                        eoW1, eob1, eoW2, eob2, out, E);
}

// Round 17
// 358.496 us; speedup vs baseline: 1.0806x; 1.0009x over previous
//
#include <hip/hip_runtime.h>
#include <hip/hip_fp16.h>
#include <math.h>

// ---------------------------------------------------------------------------
// GAT model forward. N=100k nodes, E=1.6M edges, HID=64.
// R16 changes vs R15 (358.8us, best):
//  - k_scatter_fuse blockDim 256 -> 512 (same 2048-edge chunk, 4 edges/thr):
//    782 blocks x 8 waves = 6256 waves (~76% occupancy) vs 3128 (31% measured)
//    -- the kernel is pure latency-bound (VALU 8.8%), wave count was the cap.
//  - everything else identical to R15. Edge head at structural 8-XCD
//    replication floor (184MB/3.1TB/s, invariant across 8 rounds).
// ---------------------------------------------------------------------------

typedef _Float16 half8_t __attribute__((ext_vector_type(8)));
typedef float floatx4 __attribute__((ext_vector_type(4)));

// Phase 1: bucket edges by dst>>7 (rank trick). Block 0 also computes
// vsd = [g2W@g2as ; g2W@g2ad] for k_hw_mfma's factored alpha MFMA.
// Then grid-stride fuse1 tail: hw1 = fp16(x@Mc+c), H=4 alphas.
// blockDim = 512 (8 waves) for latency-bound occupancy.
__global__ __launch_bounds__(512) void k_scatter_fuse(
    const int* __restrict__ src, const int* __restrict__ dst,
    int E, int NB, int cap, int* cursor,
    unsigned int* __restrict__ ebuf,
    const float* __restrict__ x,
    const float* __restrict__ encW, const float* __restrict__ encb,
    const float* __restrict__ g1W,
    const float* __restrict__ g1as, const float* __restrict__ g1ad,
    const float* __restrict__ g2W,
    const float* __restrict__ g2as, const float* __restrict__ g2ad,
    float* __restrict__ vsd,
    __half* __restrict__ hw, float* __restrict__ alpha_s,
    float* __restrict__ alpha_d, int n){
  __shared__ int hist[800];
  __shared__ int base[800];
  __shared__ float McS[192];
  int t = threadIdx.x;                  // blockDim = 512
  if (t < 64){                          // per-block Mc (g1W is L2-resident)
    float m0 = 0.f, m1 = 0.f, cc = 0.f;
    for (int k = 0; k < 64; ++k){
      float g = g1W[k * 64 + t];
      m0 = fmaf(encW[k], g, m0);
      m1 = fmaf(encW[64 + k], g, m1);
      cc = fmaf(encb[k], g, cc);
    }
    McS[t] = m0; McS[64 + t] = m1; McS[128 + t] = cc;
  }
  if (blockIdx.x == 0 && t >= 64 && t < 128){  // vsd on a different wave
    int k = t - 64;
    float vs = 0.f, vd = 0.f;
    for (int ch = 0; ch < 64; ++ch){
      float g = g2W[k * 64 + ch];
      vs = fmaf(g, g2as[ch], vs);
      vd = fmaf(g, g2ad[ch], vd);
    }
    vsd[k] = vs; vsd[64 + k] = vd;
  }
  for (int i = t; i < NB; i += 512) hist[i] = 0;
  __syncthreads();
  int cbase = blockIdx.x * 2048;
  int sv[4], bk[4], dl[4], rk[4];
  #pragma unroll
  for (int i = 0; i < 4; ++i){
    int e = cbase + i * 512 + t;
    if (e < E){
      int d = dst[e];
      sv[i] = src[e]; bk[i] = d >> 7; dl[i] = d & 127;
      rk[i] = atomicAdd(&hist[bk[i]], 1);   // rank within (block,bucket)
    } else bk[i] = -1;
  }
  __syncthreads();
  for (int i = t; i < NB; i += 512){
    int c = hist[i];
    base[i] = (c > 0) ? (i * cap + atomicAdd(&cursor[i], c)) : 0;
  }
  __syncthreads();
  #pragma unroll
  for (int i = 0; i < 4; ++i){
    if (bk[i] >= 0){
      int p = base[bk[i]] + rk[i];
      if (p < (bk[i] + 1) * cap)        // overflow guard (never fires in practice)
        ebuf[p] = (unsigned)sv[i] | ((unsigned)dl[i] << 17);
    }
  }
  // ---- fuse1 tail: grid-stride over n*64 channels ----
  int total = n * 64;
  int lane = t & 63;
  for (int idx = blockIdx.x * 512 + t; idx < total; idx += gridDim.x * 512){
    int node = idx >> 6;                // j == lane (idx base multiple of 64)
    float acc = fmaf(x[node * 2 + 0], McS[lane],
                fmaf(x[node * 2 + 1], McS[64 + lane], McS[128 + lane]));
    hw[idx] = __float2half(acc);
    float ps = acc * g1as[lane];
    float pd = acc * g1ad[lane];
    #pragma unroll
    for (int off = 1; off < 16; off <<= 1){
      ps += __shfl_xor(ps, off);
      pd += __shfl_xor(pd, off);
    }
    if ((lane & 15) == 0){
      int h = lane >> 4;
      alpha_s[node * 4 + h] = ps;
      alpha_d[node * 4 + h] = pd;
    }
  }
}

// Phase 2: one block (256 thr) per 128-node bucket. Sort in LDS ->
// rowrange (int2) + dst-sorted packed ebuf.
__global__ void k_bucket_build(const int* __restrict__ cursor, int cap, int N,
                               unsigned int* ebuf, int2* __restrict__ rowrange){
  __shared__ unsigned int ent[2700];
  __shared__ unsigned short rank[2700];
  __shared__ int cnts[128];
  __shared__ int aux[128];
  int b = blockIdx.x, t = threadIdx.x;  // blockDim = 256
  int base = b * cap;
  int cnt = cursor[b];
  if (cnt > cap) cnt = cap;
  for (int i = t; i < cnt; i += 256) ent[i] = ebuf[base + i];
  if (t < 128) cnts[t] = 0;
  __syncthreads();
  for (int i = t; i < cnt; i += 256)
    rank[i] = (unsigned short)atomicAdd(&cnts[ent[i] >> 17], 1);
  __syncthreads();
  int v = 0;
  if (t < 128){ v = cnts[t]; aux[t] = v; }
  __syncthreads();
  for (int off = 1; off < 128; off <<= 1){
    int x = 0;
    if (t < 128 && t >= off) x = aux[t - off];
    __syncthreads();
    if (t < 128) aux[t] += x;
    __syncthreads();
  }
  if (t < 128){
    int incl = aux[t];
    int node = (b << 7) + t;
    if (node < N) rowrange[node] = make_int2(base + incl - v, base + incl);
    cnts[t] = incl - v;                 // per-node segment start (no atomics)
  }
  __syncthreads();
  for (int i = t; i < cnt; i += 256){
    unsigned int en = ent[i];
    int pos = cnts[en >> 17] + (int)rank[i];
    ebuf[base + pos] = en;              // keep packed (src|dl<<17)
  }
}

// MFMA GEMM: hw2 = fp16(h1 @ g2W); alphas via factored MFMA on wave 0:
// alpha_{s,d}[node] = h1[node,:] . vsd  (B cols [v_s|v_d|0..]).
// Zero barriers, zero LDS.
__global__ __launch_bounds__(256) void k_hw_mfma(
    const __half* __restrict__ hin, const float* __restrict__ W,
    const float* __restrict__ vsd,
    __half* __restrict__ hw, float* __restrict__ alpha_s,
    float* __restrict__ alpha_d, int n){
  int t = threadIdx.x;
  int lane = t & 63, wave = t >> 6;
  int l15 = lane & 15, quad = lane >> 4;
  int ch = wave * 16 + l15;
  half8_t b0, b1;
  #pragma unroll
  for (int j = 0; j < 8; ++j){
    b0[j] = (_Float16)W[(quad * 8 + j) * 64 + ch];
    b1[j] = (_Float16)W[(quad * 8 + j + 32) * 64 + ch];
  }
  half8_t bA0 = {0,0,0,0,0,0,0,0}, bA1 = {0,0,0,0,0,0,0,0};
  if (wave == 0 && l15 < 2){
    const float* v = vsd + l15 * 64;
    #pragma unroll
    for (int j = 0; j < 8; ++j){
      bA0[j] = (_Float16)v[quad * 8 + j];
      bA1[j] = (_Float16)v[quad * 8 + j + 32];
    }
  }
  int base = blockIdx.x * 64;
  for (int it = 0; it < 4; ++it){
    int tb = base + it * 16;
    if (tb >= n) break;
    int arn = tb + l15; if (arn >= n) arn = n - 1;
    const __half* arow = hin + (size_t)arn * 64 + quad * 8;
    half8_t a0 = *(const half8_t*)arow;
    half8_t a1 = *(const half8_t*)(arow + 32);
    floatx4 acc = {0.f, 0.f, 0.f, 0.f};
    acc = __builtin_amdgcn_mfma_f32_16x16x32_f16(a0, b0, acc, 0, 0, 0);
    acc = __builtin_amdgcn_mfma_f32_16x16x32_f16(a1, b1, acc, 0, 0, 0);
    #pragma unroll
    for (int r = 0; r < 4; ++r){
      int node = tb + quad * 4 + r;
      if (node < n) hw[(size_t)node * 64 + ch] = __float2half(acc[r]);
    }
    if (wave == 0){
      floatx4 accA = {0.f, 0.f, 0.f, 0.f};
      accA = __builtin_amdgcn_mfma_f32_16x16x32_f16(a0, bA0, accA, 0, 0, 0);
      accA = __builtin_amdgcn_mfma_f32_16x16x32_f16(a1, bA1, accA, 0, 0, 0);
      if (l15 < 2){
        float* dstp = (l15 == 0) ? alpha_s : alpha_d;
        #pragma unroll
        for (int r = 0; r < 4; ++r){
          int node = tb + quad * 4 + r;
          if (node < n) dstp[node] = accA[r];
        }
      }
    }
  }
}

// Wave = 1 destination node, 8 edge-groups x 8 lanes; lane jj owns channels
// 8jj..8jj+7 (one 16B fp16 load per edge). Numerator computed in-loop from
// the L2-resident alpha tables. [R8 gather structure: best measured.]
template<int H, bool ELU_ACT>
__global__ void k_agg(const __half* __restrict__ hw,
                      const float* __restrict__ alpha_s, const float* __restrict__ alpha_d,
                      const int2* __restrict__ rowrange,
                      const unsigned int* __restrict__ ebuf,
                      const float* __restrict__ bias, __half* __restrict__ hout, int n){
  int node = (blockIdx.x * blockDim.x + threadIdx.x) >> 6;
  int lane = threadIdx.x & 63;
  int g = lane >> 3, jj = lane & 7;
  if (node >= n) return;
  int hidx = (jj * H) >> 3;                // head of channels 8jj..8jj+7
  int2 rr = rowrange[node];
  int start = rr.x, end = rr.y;
  float adn = alpha_d[node * H + hidx];
  float acc[8] = {0.f,0.f,0.f,0.f,0.f,0.f,0.f,0.f};
  float psum = 0.f;
  if (g == 0){                             // self loop (group 0 only)
    float a = alpha_s[node * H + hidx] + adn;
    a = a > 0.f ? a : 0.2f * a;
    float p = __expf(a);
    psum = p;
    float4 rv = *(const float4*)(hw + (size_t)node * 64 + jj * 8);
    const __half2* hp = (const __half2*)&rv;
    #pragma unroll
    for (int k = 0; k < 4; ++k){
      float2 f = __half22float2(hp[k]);
      acc[2 * k] = p * f.x; acc[2 * k + 1] = p * f.y;
    }
  }
  int i = start + g;
  for (; i + 8 < end; i += 16){
    unsigned int e0 = ebuf[i], e1 = ebuf[i + 8];
    int s0 = e0 & 0x1FFFF, s1 = e1 & 0x1FFFF;
    float a0 = alpha_s[s0 * H + hidx] + adn;
    float a1 = alpha_s[s1 * H + hidx] + adn;
    a0 = a0 > 0.f ? a0 : 0.2f * a0;
    a1 = a1 > 0.f ? a1 : 0.2f * a1;
    float p0 = __expf(a0), p1 = __expf(a1);
    float4 r0 = *(const float4*)(hw + (size_t)s0 * 64 + jj * 8);
    float4 r1 = *(const float4*)(hw + (size_t)s1 * 64 + jj * 8);
    const __half2* h0 = (const __half2*)&r0;
    const __half2* h1 = (const __half2*)&r1;
    psum += p0 + p1;
    #pragma unroll
    for (int k = 0; k < 4; ++k){
      float2 f0 = __half22float2(h0[k]);
      float2 f1 = __half22float2(h1[k]);
      acc[2 * k]     = fmaf(p0, f0.x, fmaf(p1, f1.x, acc[2 * k]));
      acc[2 * k + 1] = fmaf(p0, f0.y, fmaf(p1, f1.y, acc[2 * k + 1]));
    }
  }
  if (i < end){
    unsigned int en = ebuf[i];
    int s = en & 0x1FFFF;
    float a = alpha_s[s * H + hidx] + adn;
    a = a > 0.f ? a : 0.2f * a;
    float p = __expf(a);
    float4 rv = *(const float4*)(hw + (size_t)s * 64 + jj * 8);
    const __half2* hp = (const __half2*)&rv;
    psum += p;
    #pragma unroll
    for (int k = 0; k < 4; ++k){
      float2 f = __half22float2(hp[k]);
      acc[2 * k]     = fmaf(p, f.x, acc[2 * k]);
      acc[2 * k + 1] = fmaf(p, f.y, acc[2 * k + 1]);
    }
  }
  #pragma unroll
  for (int off = 8; off < 64; off <<= 1){
    psum += __shfl_xor(psum, off);
    #pragma unroll
    for (int k = 0; k < 8; ++k) acc[k] += __shfl_xor(acc[k], off);
  }
  if (g == 0){
    float inv = 1.f / (psum + 1e-16f);
    float4 bv0 = ((const float4*)bias)[2 * jj];
    float4 bv1 = ((const float4*)bias)[2 * jj + 1];
    float o[8];
    o[0] = fmaf(acc[0], inv, bv0.x); o[1] = fmaf(acc[1], inv, bv0.y);
    o[2] = fmaf(acc[2], inv, bv0.z); o[3] = fmaf(acc[3], inv, bv0.w);
    o[4] = fmaf(acc[4], inv, bv1.x); o[5] = fmaf(acc[5], inv, bv1.y);
    o[6] = fmaf(acc[6], inv, bv1.z); o[7] = fmaf(acc[7], inv, bv1.w);
    if (ELU_ACT){
      #pragma unroll
      for (int k = 0; k < 8; ++k) o[k] = o[k] > 0.f ? o[k] : (__expf(o[k]) - 1.f);
    }
    half8_t hv;
    #pragma unroll
    for (int k = 0; k < 8; ++k) hv[k] = (_Float16)o[k];
    *(half8_t*)(hout + (size_t)node * 64 + jj * 8) = hv;
  }
}

// Fused heads GEMMs over h2 (fp16): P1/P2 fp16 + node head, 6 MFMAs/wave-tile.
__global__ __launch_bounds__(256) void k_heads_mfma(
    const __half* __restrict__ h, const float* __restrict__ eoW1,
    const float* __restrict__ noW1, const float* __restrict__ nob1,
    const float* __restrict__ noW2, const float* __restrict__ nob2,
    __half* __restrict__ P1, __half* __restrict__ P2,
    float* __restrict__ outN, int n){
  __shared__ float redP[4][16][2];
  int t = threadIdx.x;
  int lane = t & 63, wave = t >> 6;
  int l15 = lane & 15, quad = lane >> 4;
  int ch = wave * 16 + l15;
  half8_t bP1a, bP1b, bP2a, bP2b, bNa, bNb;
  #pragma unroll
  for (int j = 0; j < 8; ++j){
    int k0 = quad * 8 + j, k1 = k0 + 32;
    bP1a[j] = (_Float16)eoW1[k0 * 64 + ch];
    bP1b[j] = (_Float16)eoW1[k1 * 64 + ch];
    bP2a[j] = (_Float16)eoW1[(k0 + 64) * 64 + ch];
    bP2b[j] = (_Float16)eoW1[(k1 + 64) * 64 + ch];
    bNa[j]  = (_Float16)noW1[k0 * 64 + ch];
    bNb[j]  = (_Float16)noW1[k1 * 64 + ch];
  }
  float b1v = nob1[ch];
  float w20 = noW2[ch * 2 + 0], w21 = noW2[ch * 2 + 1];
  float b20 = nob2[0], b21 = nob2[1];
  int base = blockIdx.x * 64;
  for (int it = 0; it < 4; ++it){
    int tb = base + it * 16;
    if (tb >= n) break;
    int arn = tb + l15; if (arn >= n) arn = n - 1;
    const __half* arow = h + (size_t)arn * 64 + quad * 8;
    half8_t a0 = *(const half8_t*)arow;
    half8_t a1 = *(const half8_t*)(arow + 32);
    floatx4 ac1 = {0.f,0.f,0.f,0.f}, ac2 = {0.f,0.f,0.f,0.f}, acN = {0.f,0.f,0.f,0.f};
    ac1 = __builtin_amdgcn_mfma_f32_16x16x32_f16(a0, bP1a, ac1, 0, 0, 0);
    ac1 = __builtin_amdgcn_mfma_f32_16x16x32_f16(a1, bP1b, ac1, 0, 0, 0);
    ac2 = __builtin_amdgcn_mfma_f32_16x16x32_f16(a0, bP2a, ac2, 0, 0, 0);
    ac2 = __builtin_amdgcn_mfma_f32_16x16x32_f16(a1, bP2b, ac2, 0, 0, 0);
    acN = __builtin_amdgcn_mfma_f32_16x16x32_f16(a0, bNa, acN, 0, 0, 0);
    acN = __builtin_amdgcn_mfma_f32_16x16x32_f16(a1, bNb, acN, 0, 0, 0);
    float p0[4], p1[4];
    #pragma unroll
    for (int r = 0; r < 4; ++r){
      int node = tb + quad * 4 + r;
      if (node < n){
        P1[(size_t)node * 64 + ch] = __float2half(ac1[r]);
        P2[(size_t)node * 64 + ch] = __float2half(ac2[r]);
      }
      float v = acN[r] + b1v;
      v = v > 0.f ? v : 0.01f * v;
      p0[r] = v * w20;
      p1[r] = v * w21;
      #pragma unroll
      for (int off = 1; off < 16; off <<= 1){
        p0[r] += __shfl_xor(p0[r], off);
        p1[r] += __shfl_xor(p1[r], off);
      }
    }
    if (l15 == 0){
      #pragma unroll
      for (int r = 0; r < 4; ++r){
        redP[wave][quad * 4 + r][0] = p0[r];
        redP[wave][quad * 4 + r][1] = p1[r];
      }
    }
    __syncthreads();
    if (t < 16 && tb + t < n){
      float s0 = redP[0][t][0] + redP[1][t][0] + redP[2][t][0] + redP[3][t][0];
      float s1 = redP[0][t][1] + redP[1][t][1] + redP[2][t][1] + redP[3][t][1];
      outN[(size_t)(tb + t) * 2 + 0] = tanhf(s0 + b20);
      outN[(size_t)(tb + t) * 2 + 1] = tanhf(s1 + b21);
    }
    __syncthreads();
  }
}

// 16 edges per wave-iteration: 8 groups of 8 lanes, each group handles edges
// e and e+8 (2x unroll -> 32 gathers in flight per wave).
__global__ void k_edge_head(const __half* __restrict__ P1h, const __half* __restrict__ P2h,
                            const int* __restrict__ src, const int* __restrict__ dst,
                            const float* __restrict__ eattr, const float* __restrict__ eoW1,
                            const float* __restrict__ b1, const float* __restrict__ W2,
                            const float* __restrict__ b2, float* __restrict__ out, int E){
  int lane = threadIdx.x & 63;
  int jj = lane & 7, q = lane >> 3;
  int wid = (blockIdx.x * blockDim.x + threadIdx.x) >> 6;
  int nw = (gridDim.x * blockDim.x) >> 6;

  const float4* rAq = (const float4*)(eoW1 + 8192);
  const float4* rBq = (const float4*)(eoW1 + 8256);
  const float4* b1q = (const float4*)b1;
  const float4* w2q = (const float4*)W2;
  float4 tA0 = rAq[2 * jj], tA1 = rAq[2 * jj + 1];
  float4 tB0 = rBq[2 * jj], tB1 = rBq[2 * jj + 1];
  float4 tb0 = b1q[2 * jj], tb1 = b1q[2 * jj + 1];
  float4 tw0 = w2q[2 * jj], tw1 = w2q[2 * jj + 1];
  float ra[8] = {tA0.x, tA0.y, tA0.z, tA0.w, tA1.x, tA1.y, tA1.z, tA1.w};
  float rb[8] = {tB0.x, tB0.y, tB0.z, tB0.w, tB1.x, tB1.y, tB1.z, tB1.w};
  float bb[8] = {tb0.x, tb0.y, tb0.z, tb0.w, tb1.x, tb1.y, tb1.z, tb1.w};
  float w2[8] = {tw0.x, tw0.y, tw0.z, tw0.w, tw1.x, tw1.y, tw1.z, tw1.w};
  float b2v = b2[0];

  const float4* P1q = (const float4*)P1h;
  const float4* P2q = (const float4*)P2h;
  const float2* eav = (const float2*)eattr;

  int groups = (E + 15) >> 4;
  for (int g = wid; g < groups; g += nw){
    int e0 = g * 16 + q, e1 = e0 + 8;
    bool act0 = (e0 < E), act1 = (e1 < E);
    float p0 = 0.f, p1 = 0.f;
    if (act0){
      int s = src[e0], d = dst[e0];
      float2 ea = eav[e0];
      float4 g1 = P1q[(size_t)s * 8 + jj];
      float4 g2 = P2q[(size_t)d * 8 + jj];
      const __half2* h1 = (const __half2*)&g1;
      const __half2* h2 = (const __half2*)&g2;
      #pragma unroll
      for (int k = 0; k < 4; ++k){
        float2 u = __half22float2(h1[k]);
        float2 w = __half22float2(h2[k]);
        float ta = u.x + w.x + bb[2 * k];
        float tb = u.y + w.y + bb[2 * k + 1];
        ta = fmaf(ea.x, ra[2 * k], fmaf(ea.y, rb[2 * k], ta));
        tb = fmaf(ea.x, ra[2 * k + 1], fmaf(ea.y, rb[2 * k + 1], tb));
        ta = ta > 0.f ? ta : 0.01f * ta;
        tb = tb > 0.f ? tb : 0.01f * tb;
        p0 = fmaf(ta, w2[2 * k], fmaf(tb, w2[2 * k + 1], p0));
      }
    }
    if (act1){
      int s = src[e1], d = dst[e1];
      float2 ea = eav[e1];
      float4 g1 = P1q[(size_t)s * 8 + jj];
      float4 g2 = P2q[(size_t)d * 8 + jj];
      const __half2* h1 = (const __half2*)&g1;
      const __half2* h2 = (const __half2*)&g2;
      #pragma unroll
      for (int k = 0; k < 4; ++k){
        float2 u = __half22float2(h1[k]);
        float2 w = __half22float2(h2[k]);
        float ta = u.x + w.x + bb[2 * k];
        float tb = u.y + w.y + bb[2 * k + 1];
        ta = fmaf(ea.x, ra[2 * k], fmaf(ea.y, rb[2 * k], ta));
        tb = fmaf(ea.x, ra[2 * k + 1], fmaf(ea.y, rb[2 * k + 1], tb));
        ta = ta > 0.f ? ta : 0.01f * ta;
        tb = tb > 0.f ? tb : 0.01f * tb;
        p1 = fmaf(ta, w2[2 * k], fmaf(tb, w2[2 * k + 1], p1));
      }
    }
    #pragma unroll
    for (int off = 1; off < 8; off <<= 1){
      p0 += __shfl_xor(p0, off);
      p1 += __shfl_xor(p1, off);
    }
    if (jj == 0){
      if (act0) out[e0] = tanhf(p0 + b2v);
      if (act1) out[e1] = tanhf(p1 + b2v);
    }
  }
}

extern "C" void kernel_launch(void* const* d_in, const int* in_sizes, int n_in,
                              void* d_out, int out_size, void* d_ws, size_t ws_size,
                              hipStream_t stream){
  const float* x    = (const float*)d_in[0];
  const int*   eidx = (const int*)  d_in[1];
  const float* ea   = (const float*)d_in[2];
  const float* encW = (const float*)d_in[3];
  const float* encb = (const float*)d_in[4];
  const float* g1W  = (const float*)d_in[5];
  const float* g1as = (const float*)d_in[6];
  const float* g1ad = (const float*)d_in[7];
  const float* g1b  = (const float*)d_in[8];
  const float* g2W  = (const float*)d_in[9];
  const float* g2as = (const float*)d_in[10];
  const float* g2ad = (const float*)d_in[11];
  const float* g2b  = (const float*)d_in[12];
  const float* noW1 = (const float*)d_in[13];
  const float* nob1 = (const float*)d_in[14];
  const float* noW2 = (const float*)d_in[15];
  const float* nob2 = (const float*)d_in[16];
  const float* eoW1 = (const float*)d_in[17];
  const float* eob1 = (const float*)d_in[18];
  const float* eoW2 = (const float*)d_in[19];
  const float* eob2 = (const float*)d_in[20];

  const int N = in_sizes[0] / 2;
  const int E = in_sizes[1] / 2;
  const int* src = eidx;
  const int* dst = eidx + E;

  const int NB = (N + 127) >> 7;         // buckets of 128 nodes (<= 800)
  int avg = (E + NB - 1) / NB;
  int cap = avg + avg / 4 + 64;          // ~25% headroom
  if (cap > 2700) cap = 2700;            // LDS limit in k_bucket_build

  // workspace layout
  char* ws = (char*)d_ws;
  size_t off = 0;
  auto alloc = [&](size_t bytes) -> void* {
    void* p = ws + off;
    off = (off + bytes + 255) & ~(size_t)255;
    return p;
  };
  __half* bufA  = (__half*)alloc((size_t)N * 64 * 2);   // h1 -> h2 (fp16)
  __half* bufH  = (__half*)alloc((size_t)N * 64 * 2);   // hw1 -> hw2
  __half* P1h   = (__half*)alloc((size_t)N * 64 * 2);
  __half* P2h   = (__half*)alloc((size_t)N * 64 * 2);
  float*  as    = (float*) alloc((size_t)N * 4 * 4);
  float*  ad    = (float*) alloc((size_t)N * 4 * 4);
  int2* rowrange = (int2*) alloc((size_t)N * 8);
  unsigned int* ebuf = (unsigned int*)alloc((size_t)NB * cap * 4);   // packed entries
  int* cursor   = (int*)   alloc((size_t)NB * 4);
  float* vsd    = (float*) alloc(128 * 4);              // [g2W@g2as ; g2W@g2ad]

  // ---- CSR build phase 1 + layer-1 hw/alphas + vsd precompute (merged) ----
  hipMemsetAsync(cursor, 0, (size_t)NB * 4, stream);
  k_scatter_fuse<<<(E + 2047) / 2048, 512, 0, stream>>>(
      src, dst, E, NB, cap, cursor, ebuf,
      x, encW, encb, g1W, g1as, g1ad, g2W, g2as, g2ad, vsd, bufH, as, ad, N);
  // ---- CSR build phase 2 (lean sort) ----
  k_bucket_build<<<NB, 256, 0, stream>>>(cursor, cap, N, ebuf, rowrange);
  // ---- layer-1 aggregation + ELU (numerator inline) ----
  k_agg<4, true><<<(N + 3) / 4, 256, 0, stream>>>(bufH, as, ad,
                                                  rowrange, ebuf, g1b, bufA, N);
  // ---- GAT layer 2 (alphas via factored MFMA; numerator inline in agg) ----
  k_hw_mfma<<<(N + 63) / 64, 256, 0, stream>>>(bufA, g2W, vsd, bufH, as, ad, N);
  k_agg<1, false><<<(N + 3) / 4, 256, 0, stream>>>(bufH, as, ad,
                                                   rowrange, ebuf, g2b, bufA, N);
  // ---- heads (fused P1/P2 + node head) ----
  float* out = (float*)d_out;
  k_heads_mfma<<<(N + 63) / 64, 256, 0, stream>>>(bufA, eoW1, noW1, nob1, noW2, nob2,
                                                  P1h, P2h, out + E, N);
  k_edge_head<<<2048, 256, 0, stream>>>(P1h, P2h, src, dst, ea,
                                        eoW1, eob1, eoW2, eob2, out, E);
}